// Round 4
// baseline (784.564 us; speedup 1.0000x reference)
//
#include <hip/hip_runtime.h>
#include <math.h>
#include <stdint.h>

// ---------------- problem constants ----------------
#define BB    2
#define TT    4096
#define CDIM  2048
#define NHQ   16
#define NKV   4
#define HD    128
#define HALF  64
#define NREP  4
#define RBLK  16
#define NB    256
#define TOPK  64

#define MROWS (BB * TT)                    // 8192
#define NQKV  (CDIM + 2 * NKV * HD)        // 3072
#define XELE  ((size_t)MROWS * CDIM)       // 16,777,216

typedef __bf16 bf16;
typedef __bf16 bf16x4 __attribute__((ext_vector_type(4)));
typedef __bf16 bf16x8 __attribute__((ext_vector_type(8)));
typedef float f32x4 __attribute__((ext_vector_type(4)));

typedef __attribute__((address_space(1))) unsigned int gu32;
typedef __attribute__((address_space(3))) unsigned int lu32;

__device__ __forceinline__ void gload_lds16(const void* g, void* l) {
  void* gv = const_cast<void*>(g);
  __builtin_amdgcn_global_load_lds((gu32*)gv, (lu32*)l, 16, 0, 0);
}

#define MFMA_BF16 __builtin_amdgcn_mfma_f32_16x16x32_bf16

// ---------------- split-bf16 3-term MFMA GEMM core (256x256, 8-wave, 4-phase) ----------------
// Block tile 256x256, 512 threads (8 waves as 2M x 4N), each wave 128x64 (acc[8][4]).
// A row-major MxK bf16 (hi/lo), B stored as B^T row-major NxK bf16 (hi/lo).
// acc = Ah*Bh + Ah*Bl + Al*Bh (term and K order preserved -> bitwise-stable result).
// Per K-tile (BK=32): 4 phases (one per j-column of acc); phase j = {stage 2/8
// next-tile loads, read B[j] (and all A at j==0), barrier, 24 MFMA, barrier}.
// Counted s_waitcnt vmcnt(2) once per tile at phase 0 -- the 2 loads just issued for
// tile t+1 stay in flight; never vmcnt(0) in steady state (T3+T4). setprio around MFMA
// clusters (T5). LDS 2 x 64 KiB double buffer (1 block/CU, m201 operating point).
// Staging keeps the source-chunk XOR swizzle (measured 0 bank conflicts).

#define LDS_BUF 32768     // elements per buffer: Ah 8192 | Al 8192 | Bh 8192 | Bl 8192
#define OFF_AL  8192
#define OFF_BH  16384
#define OFF_BL  24576

__device__ __forceinline__ void mfma3_core256(const bf16* __restrict__ Ah,
                                              const bf16* __restrict__ Al,
                                              const bf16* __restrict__ Bh,
                                              const bf16* __restrict__ Bl,
                                              int bm, int bn,
                                              f32x4 acc[8][4]) {
  __shared__ __align__(16) bf16 smem[2 * LDS_BUF];
  const int tid = threadIdx.x;
  const int wave = tid >> 6, lane = tid & 63;
  const int lr4 = lane >> 2;
  // staging source-chunk swizzle: LDS slot chunk (lane&3) receives global chunk
  // (lane&3) ^ ((row>>1)&3); row = 16*call + (lane>>2) -> (lane>>3)&3 for all calls.
  const int cgs = (lane & 3) ^ ((lane >> 3) & 3);
  const size_t stageoff = (size_t)lr4 * CDIM + cgs * 8;

  // 64 staging wave-calls of 1 KiB per K-tile, 8 per wave.
  const bf16* gp[8];
  int loff[8];
#pragma unroll
  for (int u = 0; u < 8; ++u) {
    int c = wave * 8 + u;
    const bf16* base;
    int lb;
    if (c < 16)      { base = Ah + (size_t)(bm + c * 16) * CDIM;        lb = c * 512; }
    else if (c < 32) { base = Al + (size_t)(bm + (c - 16) * 16) * CDIM; lb = OFF_AL + (c - 16) * 512; }
    else if (c < 48) { base = Bh + (size_t)(bn + (c - 32) * 16) * CDIM; lb = OFF_BH + (c - 32) * 512; }
    else             { base = Bl + (size_t)(bn + (c - 48) * 16) * CDIM; lb = OFF_BL + (c - 48) * 512; }
    gp[u] = base + stageoff;
    loff[u] = lb;
  }

  const int wr = wave >> 2, wc = wave & 3;          // 2M x 4N wave grid
  const int fr = lane & 15, lg = lane >> 4;
  // fragment read: row r, chunk lg stored at chunk lg ^ ((r>>1)&3) = lg ^ ((fr>>1)&3)
  const int chunk = (lg ^ ((fr >> 1) & 3)) << 3;
  const int arow = wr * 128 + fr;
  const int brow = wc * 64 + fr;

  // prologue: stage K-tile 0 into buffer 0
#pragma unroll
  for (int u = 0; u < 8; ++u) gload_lds16(gp[u], &smem[loff[u]]);

  for (int t = 0; t < 64; ++t) {
    const bf16* cb = &smem[(t & 1) * LDS_BUF];
    bf16* nb = &smem[((t + 1) & 1) * LDS_BUF];
    const int kk = (t + 1) * 32;
    const bool nlast = (t < 63);

    // ---- phase 0: stage u0,u1 -> counted wait -> barrier -> all A + B0 -> 24 MFMA ----
    if (nlast) {
      gload_lds16(gp[0] + kk, nb + loff[0]);
      gload_lds16(gp[1] + kk, nb + loff[1]);
      // tile t's 8 loads are the oldest; keep the 2 just issued in flight
      asm volatile("s_waitcnt vmcnt(2)" ::: "memory");
    } else {
      asm volatile("s_waitcnt vmcnt(0)" ::: "memory");
    }
    __builtin_amdgcn_s_barrier();
    asm volatile("" ::: "memory");

    bf16x8 fah[8], fal[8];
#pragma unroll
    for (int i = 0; i < 8; ++i) {
      fah[i] = *(const bf16x8*)&cb[(arow + i * 16) * 32 + chunk];
      fal[i] = *(const bf16x8*)&cb[OFF_AL + (arow + i * 16) * 32 + chunk];
    }
    {
      bf16x8 fbh = *(const bf16x8*)&cb[OFF_BH + brow * 32 + chunk];
      bf16x8 fbl = *(const bf16x8*)&cb[OFF_BL + brow * 32 + chunk];
      __builtin_amdgcn_s_setprio(1);
#pragma unroll
      for (int i = 0; i < 8; ++i) {
        acc[i][0] = MFMA_BF16(fah[i], fbh, acc[i][0], 0, 0, 0);
        acc[i][0] = MFMA_BF16(fah[i], fbl, acc[i][0], 0, 0, 0);
        acc[i][0] = MFMA_BF16(fal[i], fbh, acc[i][0], 0, 0, 0);
      }
      __builtin_amdgcn_s_setprio(0);
    }
    asm volatile("" ::: "memory");
    __builtin_amdgcn_s_barrier();
    asm volatile("" ::: "memory");

    // ---- phases 1..3: stage u(2j),u(2j+1), read B[j], barrier, 24 MFMA ----
#pragma unroll
    for (int j = 1; j < 4; ++j) {
      if (nlast) {
        gload_lds16(gp[2 * j] + kk, nb + loff[2 * j]);
        gload_lds16(gp[2 * j + 1] + kk, nb + loff[2 * j + 1]);
      }
      bf16x8 fbh = *(const bf16x8*)&cb[OFF_BH + (brow + j * 16) * 32 + chunk];
      bf16x8 fbl = *(const bf16x8*)&cb[OFF_BL + (brow + j * 16) * 32 + chunk];
      asm volatile("" ::: "memory");
      __builtin_amdgcn_s_barrier();
      __builtin_amdgcn_s_setprio(1);
#pragma unroll
      for (int i = 0; i < 8; ++i) {
        acc[i][j] = MFMA_BF16(fah[i], fbh, acc[i][j], 0, 0, 0);
        acc[i][j] = MFMA_BF16(fah[i], fbl, acc[i][j], 0, 0, 0);
        acc[i][j] = MFMA_BF16(fal[i], fbh, acc[i][j], 0, 0, 0);
      }
      __builtin_amdgcn_s_setprio(0);
      asm volatile("" ::: "memory");
      __builtin_amdgcn_s_barrier();
      asm volatile("" ::: "memory");
    }
  }
}

// XCD-aware bijective swizzle (T1): dispatch round-robins XCDs on raw bid; give XCD i
// a contiguous logical range decoded x-fastest so each XCD owns a few M-row panels
// across all column blocks (A panel stays in that XCD's 4 MB L2).
__device__ __forceinline__ void xcd_swizzle(int& by, int& bx) {
  const int nwgx = gridDim.x;
  const int nwg = nwgx * gridDim.y;           // divisible by 8 for our grids
  const int cpx = nwg >> 3;
  const int bid = blockIdx.y * nwgx + blockIdx.x;
  const int l = (bid & 7) * cpx + (bid >> 3);
  by = l / nwgx;
  bx = l - by * nwgx;
}

__global__ __launch_bounds__(512, 1) void csa_gemm_qkv(const bf16* __restrict__ xh,
                                                       const bf16* __restrict__ xl,
                                                       const bf16* __restrict__ wth,
                                                       const bf16* __restrict__ wtl,
                                                       float* __restrict__ qb,
                                                       float* __restrict__ kb,
                                                       float* __restrict__ vb) {
  f32x4 acc[8][4] = {};
  int by, bx;
  xcd_swizzle(by, bx);
  const int bm = by << 8, bn = bx << 8;
  mfma3_core256(xh, xl, wth, wtl, bm, bn, acc);
  const int wave = threadIdx.x >> 6, lane = threadIdx.x & 63;
  const int wr = wave >> 2, wc = wave & 3;
  const int fr = lane & 15, lg = lane >> 4;
  // 256-wide column tiles align with the q|k|v 512-boundaries (bn multiples of 256)
  float* dst; int ncols, colofs;
  if (bn < CDIM)            { dst = qb; ncols = CDIM; colofs = bn; }
  else if (bn < CDIM + 512) { dst = kb; ncols = 512;  colofs = bn - CDIM; }
  else                      { dst = vb; ncols = 512;  colofs = bn - CDIM - 512; }
#pragma unroll
  for (int i = 0; i < 8; ++i)
#pragma unroll
    for (int j = 0; j < 4; ++j) {
      int row0 = bm + wr * 128 + i * 16 + (lg << 2);
      int col = colofs + wc * 64 + j * 16 + fr;
#pragma unroll
      for (int r = 0; r < 4; ++r)
        dst[(size_t)(row0 + r) * ncols + col] = acc[i][j][r];
    }
}

__global__ __launch_bounds__(512, 1) void csa_gemm_wo(const bf16* __restrict__ ah,
                                                      const bf16* __restrict__ al,
                                                      const bf16* __restrict__ wth,
                                                      const bf16* __restrict__ wtl,
                                                      float* __restrict__ C) {
  f32x4 acc[8][4] = {};
  int by, bx;
  xcd_swizzle(by, bx);
  const int bm = by << 8, bn = bx << 8;
  mfma3_core256(ah, al, wth, wtl, bm, bn, acc);
  const int wave = threadIdx.x >> 6, lane = threadIdx.x & 63;
  const int wr = wave >> 2, wc = wave & 3;
  const int fr = lane & 15, lg = lane >> 4;
#pragma unroll
  for (int i = 0; i < 8; ++i)
#pragma unroll
    for (int j = 0; j < 4; ++j) {
      int row0 = bm + wr * 128 + i * 16 + (lg << 2);
      int col = bn + wc * 64 + j * 16 + fr;
#pragma unroll
      for (int r = 0; r < 4; ++r)
        C[(size_t)(row0 + r) * CDIM + col] = acc[i][j][r];
    }
}

// ---------------- x -> hi/lo bf16 ----------------
__global__ void csa_xconv(const float4* __restrict__ x, bf16x4* __restrict__ xh,
                          bf16x4* __restrict__ xl) {
  int i = blockIdx.x * 256 + threadIdx.x;
  float4 v = x[i];
  bf16x4 h, l;
  h[0] = (bf16)v.x; l[0] = (bf16)(v.x - (float)h[0]);
  h[1] = (bf16)v.y; l[1] = (bf16)(v.y - (float)h[1]);
  h[2] = (bf16)v.z; l[2] = (bf16)(v.z - (float)h[2]);
  h[3] = (bf16)v.w; l[3] = (bf16)(v.w - (float)h[3]);
  xh[i] = h;
  xl[i] = l;
}

// ---------------- W (KxN) -> W^T (NxK) hi/lo bf16 ----------------
__global__ __launch_bounds__(256) void csa_wconv(const float* __restrict__ W, int N,
                                                 bf16* __restrict__ wth,
                                                 bf16* __restrict__ wtl, int rowofs) {
  __shared__ float tile[32][33];
  int k0 = blockIdx.y * 32, n0 = blockIdx.x * 32;
  int tx = threadIdx.x & 31, ty = threadIdx.x >> 5;
#pragma unroll
  for (int r = 0; r < 32; r += 8)
    tile[ty + r][tx] = W[(size_t)(k0 + ty + r) * N + n0 + tx];
  __syncthreads();
#pragma unroll
  for (int r = 0; r < 32; r += 8) {
    int n = ty + r;
    float x = tile[tx][n];
    bf16 h = (bf16)x;
    bf16 l = (bf16)(x - (float)h);
    size_t o = (size_t)(rowofs + n0 + n) * CDIM + k0 + tx;
    wth[o] = h;
    wtl[o] = l;
  }
}

// ---------------- RoPE table ----------------
__global__ void csa_rope_table(float* __restrict__ cost, float* __restrict__ sint) {
  int idx = blockIdx.x * blockDim.x + threadIdx.x;
  if (idx >= TT * HALF) return;
  int t = idx / HALF, i = idx % HALF;
  double freq = pow(10000.0, -(double)i / (double)HALF);
  double ang = (double)t * freq;
  cost[idx] = (float)cos(ang);
  sint[idx] = (float)sin(ang);
}

__global__ void csa_rope_apply(float* __restrict__ buf, const float* __restrict__ cost,
                               const float* __restrict__ sint, int nheads, int total) {
  int idx = blockIdx.x * blockDim.x + threadIdx.x;
  if (idx >= total) return;
  int i = idx % HALF;
  int h = (idx / HALF) % nheads;
  int t = (idx / (HALF * nheads)) % TT;
  int b = idx / (HALF * nheads * TT);
  float c = cost[t * HALF + i], s = sint[t * HALF + i];
  float* p = buf + ((((size_t)b * TT + t) * nheads + h) * HD) + 2 * i;
  float a = p[0], q = p[1];
  p[0] = a * c - q * s;
  p[1] = a * s + q * c;
}

// ---------------- selection path ----------------
__global__ void csa_xpart(const float* __restrict__ x, float* __restrict__ xpart) {
  int d = blockIdx.x * 256 + threadIdx.x;
  int ts = blockIdx.y;
  int b = blockIdx.z;
  float s = 0.f;
  int t0 = ts * (TT / 16);
  for (int t = t0; t < t0 + TT / 16; ++t) s += x[((size_t)b * TT + t) * CDIM + d];
  xpart[((size_t)b * 16 + ts) * CDIM + d] = s;
}

__global__ void csa_kimean(const float* __restrict__ xpart, const float* __restrict__ wik,
                           float* __restrict__ ki) {
  int b = blockIdx.x >> 7;
  int j = blockIdx.x & 127;
  int tid = threadIdx.x;
  float s = 0.f;
  for (int d = tid; d < CDIM; d += 256) {
    float xm = 0.f;
#pragma unroll
    for (int ts = 0; ts < 16; ++ts) xm += xpart[((size_t)b * 16 + ts) * CDIM + d];
    s += xm * wik[(size_t)d * HD + j];
  }
  __shared__ float red[256];
  red[tid] = s;
  __syncthreads();
  for (int off = 128; off > 0; off >>= 1) {
    if (tid < off) red[tid] += red[tid + off];
    __syncthreads();
  }
  if (tid == 0) ki[b * HD + j] = red[0] * (1.f / (float)TT);
}

__global__ void csa_u(const float* __restrict__ wiq, const float* __restrict__ ki,
                      float* __restrict__ u) {
  int idx = blockIdx.x * 256 + threadIdx.x;
  int b = idx / CDIM, d = idx % CDIM;
  float s = 0.f;
#pragma unroll 8
  for (int j = 0; j < HD; ++j) s += wiq[(size_t)d * HD + j] * ki[b * HD + j];
  u[idx] = s;
}

__global__ void csa_scores(const float* __restrict__ x, const float* __restrict__ u,
                           float* __restrict__ sc) {
  int b = blockIdx.x >> 8;
  int t = blockIdx.x & 255;
  int tid = threadIdx.x;
  float s = 0.f;
  for (int d = tid; d < CDIM; d += 256)
    s += x[((size_t)b * TT + t) * CDIM + d] * u[b * CDIM + d];
  __shared__ float red[256];
  red[tid] = s;
  __syncthreads();
  for (int off = 128; off > 0; off >>= 1) {
    if (tid < off) red[tid] += red[tid + off];
    __syncthreads();
  }
  if (tid == 0) sc[blockIdx.x] = red[0];
}

__global__ void csa_topk(const float* __restrict__ sc, int* __restrict__ topk) {
  __shared__ float val[NB];
  __shared__ float rv[256];
  __shared__ int ri[256];
  int b = blockIdx.x, tid = threadIdx.x;
  val[tid] = sc[b * NB + tid];
  __syncthreads();
  for (int it = 0; it < TOPK; ++it) {
    rv[tid] = val[tid];
    ri[tid] = tid;
    __syncthreads();
    for (int off = 128; off > 0; off >>= 1) {
      if (tid < off) {
        if (rv[tid + off] > rv[tid] ||
            (rv[tid + off] == rv[tid] && ri[tid + off] < ri[tid])) {
          rv[tid] = rv[tid + off];
          ri[tid] = ri[tid + off];
        }
      }
      __syncthreads();
    }
    if (tid == 0) {
      topk[b * TOPK + it] = ri[0];
      val[ri[0]] = -INFINITY;
    }
    __syncthreads();
  }
}

// ---------------- compress selected blocks -> split-bf16 MFMA layouts ----------------
// ckh/ckl: [b][kvh][key j (64)][dim d (128)]   (B^T layout for QK^T)
// cvth/cvtl: [b][kvh][dim d (128)][key j (64)] (B^T layout for PV)
__global__ __launch_bounds__(64) void csa_compress(const float* __restrict__ kbuf,
                                                   const float* __restrict__ vbuf,
                                                   const int* __restrict__ topk,
                                                   const float* __restrict__ cwa,
                                                   const float* __restrict__ cwb,
                                                   bf16* __restrict__ ckh,
                                                   bf16* __restrict__ ckl,
                                                   bf16* __restrict__ cvth,
                                                   bf16* __restrict__ cvtl) {
  int blk = blockIdx.x;
  int b = blk / (NKV * TOPK);
  int h = (blk / TOPK) % NKV;
  int j = blk % TOPK;
  int n = topk[b * TOPK + j];
  int l = threadIdx.x;
  float ca0 = cwa[l], ca1 = cwa[l + 64];
  float cb0 = cwb[l], cb1 = cwb[l + 64];
  float kk[RBLK][2], vv[RBLK][2], ar[RBLK], br[RBLK];
#pragma unroll
  for (int r = 0; r < RBLK; ++r) {
    int t = n * RBLK + r;
    size_t base = (((size_t)b * TT + t) * NKV + h) * HD;
    kk[r][0] = kbuf[base + l];
    kk[r][1] = kbuf[base + l + 64];
    vv[r][0] = vbuf[base + l];
    vv[r][1] = vbuf[base + l + 64];
    float pa = kk[r][0] * ca0 + kk[r][1] * ca1;
    float pb = kk[r][0] * cb0 + kk[r][1] * cb1;
    for (int off = 32; off > 0; off >>= 1) {
      pa += __shfl_xor(pa, off);
      pb += __shfl_xor(pb, off);
    }
    ar[r] = pa;
    br[r] = pb;
  }
  float ma = -INFINITY, mb = -INFINITY;
#pragma unroll
  for (int r = 0; r < RBLK; ++r) { ma = fmaxf(ma, ar[r]); mb = fmaxf(mb, br[r]); }
  float ea[RBLK], eb[RBLK], sa = 0.f, sb = 0.f;
#pragma unroll
  for (int r = 0; r < RBLK; ++r) {
    ea[r] = expf(ar[r] - ma); sa += ea[r];
    eb[r] = expf(br[r] - mb); sb += eb[r];
  }
  float isa = 1.f / sa, isb = 1.f / sb;
  float o0 = 0.f, o1 = 0.f, p0 = 0.f, p1 = 0.f;
#pragma unroll
  for (int r = 0; r < RBLK; ++r) {
    float w = 0.5f * (ea[r] * isa + eb[r] * isb);
    o0 += w * kk[r][0]; o1 += w * kk[r][1];
    p0 += w * vv[r][0]; p1 += w * vv[r][1];
  }
  size_t ckbase = ((size_t)(b * NKV + h) * 64 + j) * 128;
  bf16 h0 = (bf16)o0; ckh[ckbase + l] = h0;      ckl[ckbase + l] = (bf16)(o0 - (float)h0);
  bf16 h1 = (bf16)o1; ckh[ckbase + l + 64] = h1; ckl[ckbase + l + 64] = (bf16)(o1 - (float)h1);
  size_t vtbase = (size_t)(b * NKV + h) * (128 * 64);
  bf16 g0 = (bf16)p0; cvth[vtbase + (size_t)l * 64 + j] = g0;
  cvtl[vtbase + (size_t)l * 64 + j] = (bf16)(p0 - (float)g0);
  bf16 g1 = (bf16)p1; cvth[vtbase + (size_t)(l + 64) * 64 + j] = g1;
  cvtl[vtbase + (size_t)(l + 64) * 64 + j] = (bf16)(p1 - (float)g1);
}

// ---------------- MFMA attention: fused q-RoPE, QK^T, softmax, PV ----------------
// Rows: g = t*4 + hrep for fixed (b,kvh); 128 rows/block (32 tokens x 4 heads).
__global__ __launch_bounds__(256) void csa_attn_mfma(const float* __restrict__ qb,
                                                     const float* __restrict__ cost,
                                                     const float* __restrict__ sint,
                                                     const bf16* __restrict__ ckh_g,
                                                     const bf16* __restrict__ ckl_g,
                                                     const bf16* __restrict__ cvth_g,
                                                     const bf16* __restrict__ cvtl_g,
                                                     bf16* __restrict__ oh_g,
                                                     bf16* __restrict__ ol_g) {
  __shared__ __align__(16) bf16 sck[2][64 * 128];
  __shared__ __align__(16) bf16 sV[2][64 * 64];
  const int tid = threadIdx.x;
  const int wave = tid >> 6, lane = tid & 63;
  const int b = blockIdx.y >> 2, kvh = blockIdx.y & 3;
  const int row0 = blockIdx.x << 7;
  const int wrow = wave << 5;
  const int lr = lane & 15, lg = lane >> 4;
  const float scale = 0.08838834764831845f;  // 1/sqrt(128)

  const bf16* gkh = ckh_g + (size_t)(b * NKV + kvh) * (64 * 128);
  const bf16* gkl = ckl_g + (size_t)(b * NKV + kvh) * (64 * 128);
  const bf16* gvh = cvth_g + (size_t)(b * NKV + kvh) * (128 * 64);
  const bf16* gvl = cvtl_g + (size_t)(b * NKV + kvh) * (128 * 64);

  for (int idx = tid; idx < 1024; idx += 256) {
    int j = idx >> 4, c = idx & 15;
    int dst = (j * 16 + (c ^ (j & 15))) * 8;
    *(uint4*)&sck[0][dst] = *(const uint4*)(gkh + j * 128 + c * 8);
    *(uint4*)&sck[1][dst] = *(const uint4*)(gkl + j * 128 + c * 8);
  }
  for (int idx = tid; idx < 512; idx += 256) {
    int d = idx >> 3, c = idx & 7;
    int dst = (d * 8 + (c ^ (d & 7))) * 8;
    *(uint4*)&sV[0][dst] = *(const uint4*)(gvh + d * 64 + c * 8);
    *(uint4*)&sV[1][dst] = *(const uint4*)(gvl + d * 64 + c * 8);
  }

  bf16x8 qfh[2][4], qfl[2][4];
#pragma unroll
  for (int it = 0; it < 2; ++it)
#pragma unroll
    for (int ks = 0; ks < 4; ++ks) {
      int row = wrow + it * 16 + lr;
      int g = row0 + row;
      int t = g >> 2;
      int hh = kvh * NREP + (g & 3);
      int d0 = ks * 32 + (lg << 3);
      const float* qp = qb + (((size_t)b * TT + t) * NHQ + hh) * HD + d0;
      float4 a = *(const float4*)qp;
      float4 b4 = *(const float4*)(qp + 4);
      float4 cs = *(const float4*)&cost[t * HALF + (d0 >> 1)];
      float4 sn = *(const float4*)&sint[t * HALF + (d0 >> 1)];
      float f[8];
      f[0] = a.x * cs.x - a.y * sn.x;  f[1] = a.x * sn.x + a.y * cs.x;
      f[2] = a.z * cs.y - a.w * sn.y;  f[3] = a.z * sn.y + a.w * cs.y;
      f[4] = b4.x * cs.z - b4.y * sn.z; f[5] = b4.x * sn.z + b4.y * cs.z;
      f[6] = b4.z * cs.w - b4.w * sn.w; f[7] = b4.z * sn.w + b4.w * cs.w;
      bf16x8 h8, l8;
#pragma unroll
      for (int u = 0; u < 8; ++u) {
        h8[u] = (bf16)f[u];
        l8[u] = (bf16)(f[u] - (float)h8[u]);
      }
      qfh[it][ks] = h8;
      qfl[it][ks] = l8;
    }
  __syncthreads();

  f32x4 accS[2][4] = {};
#pragma unroll
  for (int ks = 0; ks < 4; ++ks) {
    bf16x8 kh[4], kl[4];
#pragma unroll
    for (int jt = 0; jt < 4; ++jt) {
      int row = jt * 16 + lr;
      int c = ks * 4 + lg;
      int off = (row * 16 + (c ^ (row & 15))) * 8;
      kh[jt] = *(const bf16x8*)&sck[0][off];
      kl[jt] = *(const bf16x8*)&sck[1][off];
    }
#pragma unroll
    for (int it = 0; it < 2; ++it)
#pragma unroll
      for (int jt = 0; jt < 4; ++jt) {
        accS[it][jt] = MFMA_BF16(qfh[it][ks], kh[jt], accS[it][jt], 0, 0, 0);
        accS[it][jt] = MFMA_BF16(qfh[it][ks], kl[jt], accS[it][jt], 0, 0, 0);
        accS[it][jt] = MFMA_BF16(qfl[it][ks], kh[jt], accS[it][jt], 0, 0, 0);
      }
  }

#pragma unroll
  for (int it = 0; it < 2; ++it)
#pragma unroll
    for (int r = 0; r < 4; ++r) {
      float v0 = accS[it][0][r] * scale, v1 = accS[it][1][r] * scale;
      float v2 = accS[it][2][r] * scale, v3 = accS[it][3][r] * scale;
      float m = fmaxf(fmaxf(v0, v1), fmaxf(v2, v3));
      for (int off = 8; off > 0; off >>= 1) m = fmaxf(m, __shfl_xor(m, off));
      float e0 = expf(v0 - m), e1 = expf(v1 - m), e2 = expf(v2 - m), e3 = expf(v3 - m);
      float s = e0 + e1 + e2 + e3;
      for (int off = 8; off > 0; off >>= 1) s += __shfl_xor(s, off);
      float inv = 1.f / s;
      accS[it][0][r] = e0 * inv; accS[it][1][r] = e1 * inv;
      accS[it][2][r] = e2 * inv; accS[it][3][r] = e3 * inv;
    }

  __syncthreads();

#pragma unroll
  for (int it = 0; it < 2; ++it)
#pragma unroll
    for (int jt = 0; jt < 4; ++jt)
#pragma unroll
      for (int r = 0; r < 4; ++r) {
        int row = wrow + it * 16 + (lg << 2) + r;
        int k = jt * 16 + lr;
        float p = accS[it][jt][r];
        bf16 ph = (bf16)p;
        int c = k >> 3;
        int off = (row * 8 + (c ^ (row & 7))) * 8 + (k & 7);
        sck[0][off] = ph;
        sck[1][off] = (bf16)(p - (float)ph);
      }
  __syncthreads();

  for (int half = 0; half < 2; ++half) {
    if (half) {
      __syncthreads();
      for (int idx = tid; idx < 512; idx += 256) {
        int d = idx >> 3, c = idx & 7;
        int dst = (d * 8 + (c ^ (d & 7))) * 8;
        *(uint4*)&sV[0][dst] = *(const uint4*)(gvh + (64 + d) * 64 + c * 8);
        *(uint4*)&sV[1][dst] = *(const uint4*)(gvl + (64 + d) * 64 + c * 8);
      }
      __syncthreads();
    }
    f32x4 accO[2][4] = {};
#pragma unroll
    for (int ks = 0; ks < 2; ++ks) {
      bf16x8 pah[2], pal[2], vh[4], vl[4];
#pragma unroll
      for (int it = 0; it < 2; ++it) {
        int row = wrow + it * 16 + lr;
        int c = ks * 4 + lg;
        int off = (row * 8 + (c ^ (row & 7))) * 8;
        pah[it] = *(const bf16x8*)&sck[0][off];
        pal[it] = *(const bf16x8*)&sck[1][off];
      }
#pragma unroll
      for (int jt = 0; jt < 4; ++jt) {
        int d = jt * 16 + lr;
        int c = ks * 4 + lg;
        int off = (d * 8 + (c ^ (d & 7))) * 8;
        vh[jt] = *(const bf16x8*)&sV[0][off];
        vl[jt] = *(const bf16x8*)&sV[1][off];
      }
#pragma unroll
      for (int it = 0; it < 2; ++it)
#pragma unroll
        for (int jt = 0; jt < 4; ++jt) {
          accO[it][jt] = MFMA_BF16(pah[it], vh[jt], accO[it][jt], 0, 0, 0);
          accO[it][jt] = MFMA_BF16(pah[it], vl[jt], accO[it][jt], 0, 0, 0);
          accO[it][jt] = MFMA_BF16(pal[it], vh[jt], accO[it][jt], 0, 0, 0);
        }
    }
#pragma unroll
    for (int it = 0; it < 2; ++it)
#pragma unroll
      for (int jt = 0; jt < 4; ++jt)
#pragma unroll
        for (int r = 0; r < 4; ++r) {
          int row = wrow + it * 16 + (lg << 2) + r;
          int g = row0 + row;
          int t = g >> 2;
          int hh = kvh * NREP + (g & 3);
          size_t ob = (((size_t)b * TT + t) * NHQ + hh) * HD + half * 64 + jt * 16 + lr;
          float o = accO[it][jt][r];
          bf16 oh = (bf16)o;
          oh_g[ob] = oh;
          ol_g[ob] = (bf16)(o - (float)oh);
        }
  }
}

// ---------------- launch ----------------
extern "C" void kernel_launch(void* const* d_in, const int* in_sizes, int n_in,
                              void* d_out, int out_size, void* d_ws, size_t ws_size,
                              hipStream_t stream) {
  const float* x   = (const float*)d_in[0];
  const float* wq  = (const float*)d_in[1];
  const float* wk  = (const float*)d_in[2];
  const float* wv  = (const float*)d_in[3];
  const float* wo  = (const float*)d_in[4];
  const float* wiq = (const float*)d_in[5];
  const float* wik = (const float*)d_in[6];
  const float* cwa = (const float*)d_in[7];
  const float* cwb = (const float*)d_in[8];
  float* out = (float*)d_out;

  float* qb = out;  // q fp32 lives in d_out until the final GEMM overwrites it

  float* ws = (float*)d_ws;
  float* kb   = ws;
  float* vb   = kb + (size_t)MROWS * 512;
  bf16*  xh   = (bf16*)(vb + (size_t)MROWS * 512);
  bf16*  xl   = xh + XELE;
  bf16*  wqh  = xl + XELE;
  bf16*  wql  = wqh + (size_t)NQKV * CDIM;
  float* cost = (float*)(wql + (size_t)NQKV * CDIM);
  float* sint = cost + (size_t)TT * HALF;
  float* xpart = sint + (size_t)TT * HALF;
  float* ki   = xpart + (size_t)BB * 16 * CDIM;
  float* u    = ki + BB * HD;
  float* sc   = u + BB * CDIM;
  bf16*  ckh  = (bf16*)(sc + BB * NB);
  bf16*  ckl  = ckh + (size_t)BB * NKV * 64 * 128;
  bf16*  cvth = ckl + (size_t)BB * NKV * 64 * 128;
  bf16*  cvtl = cvth + (size_t)BB * NKV * 128 * 64;
  int* topk   = (int*)(cvtl + (size_t)BB * NKV * 128 * 64);
  bf16* oh  = xh;   // attention output hi/lo reuses xh/xl
  bf16* ol_ = xl;
  bf16* woh = wqh;  // wo^T hi/lo reuses wq^T region (converted after QKV GEMM)
  bf16* wol = wql;

  // 1. input conversions
  csa_xconv<<<(XELE / 4) / 256, 256, 0, stream>>>((const float4*)x, (bf16x4*)xh, (bf16x4*)xl);
  csa_wconv<<<dim3(CDIM / 32, CDIM / 32), 256, 0, stream>>>(wq, CDIM, wqh, wql, 0);
  csa_wconv<<<dim3(512 / 32, CDIM / 32), 256, 0, stream>>>(wk, 512, wqh, wql, CDIM);
  csa_wconv<<<dim3(512 / 32, CDIM / 32), 256, 0, stream>>>(wv, 512, wqh, wql, CDIM + 512);

  // 2. fused QKV projection (256x256 tiles, 8-wave 4-phase core, XCD-swizzled)
  csa_gemm_qkv<<<dim3(NQKV / 256, MROWS / 256), 512, 0, stream>>>(xh, xl, wqh, wql, qb, kb, vb);

  // 3. wo transpose+split (reuses wq^T region)
  csa_wconv<<<dim3(CDIM / 32, CDIM / 32), 256, 0, stream>>>(wo, CDIM, woh, wol, 0);

  // 4. RoPE table + apply to k only (q RoPE fused into attention)
  csa_rope_table<<<(TT * HALF + 255) / 256, 256, 0, stream>>>(cost, sint);
  csa_rope_apply<<<(BB * TT * NKV * HALF + 255) / 256, 256, 0, stream>>>(kb, cost, sint, NKV, BB * TT * NKV * HALF);

  // 5. selection
  csa_xpart<<<dim3(CDIM / 256, 16, BB), 256, 0, stream>>>(x, xpart);
  csa_kimean<<<BB * HD, 256, 0, stream>>>(xpart, wik, ki);
  csa_u<<<(BB * CDIM) / 256, 256, 0, stream>>>(wiq, ki, u);
  csa_scores<<<BB * NB, 256, 0, stream>>>(x, u, sc);
  csa_topk<<<BB, 256, 0, stream>>>(sc, topk);

  // 6. compress selected blocks -> split-bf16 MFMA layouts
  csa_compress<<<BB * NKV * TOPK, 64, 0, stream>>>(kb, vb, topk, cwa, cwb, ckh, ckl, cvth, cvtl);

  // 7. MFMA attention (fused q-RoPE) -> split-bf16 output
  csa_attn_mfma<<<dim3((TT * NREP) / 128, BB * NKV), 256, 0, stream>>>(qb, cost, sint, ckh, ckl, cvth, cvtl, oh, ol_);

  // 8. output projection (256x256 tiles, 8-wave 4-phase core, XCD-swizzled) -> d_out
  csa_gemm_wo<<<dim3(CDIM / 256, MROWS / 256), 512, 0, stream>>>(oh, ol_, woh, wol, out);
}

// Round 5
// 735.314 us; speedup vs baseline: 1.0670x; 1.0670x over previous
//
#include <hip/hip_runtime.h>
#include <math.h>
#include <stdint.h>

// ---------------- problem constants ----------------
#define BB    2
#define TT    4096
#define CDIM  2048
#define NHQ   16
#define NKV   4
#define HD    128
#define HALF  64
#define NREP  4
#define RBLK  16
#define NB    256
#define TOPK  64

#define MROWS (BB * TT)                    // 8192
#define NQKV  (CDIM + 2 * NKV * HD)        // 3072
#define XELE  ((size_t)MROWS * CDIM)       // 16,777,216

typedef __bf16 bf16;
typedef __bf16 bf16x4 __attribute__((ext_vector_type(4)));
typedef __bf16 bf16x8 __attribute__((ext_vector_type(8)));
typedef float f32x4 __attribute__((ext_vector_type(4)));

typedef __attribute__((address_space(1))) unsigned int gu32;
typedef __attribute__((address_space(3))) unsigned int lu32;

__device__ __forceinline__ void gload_lds16(const void* g, void* l) {
  void* gv = const_cast<void*>(g);
  __builtin_amdgcn_global_load_lds((gu32*)gv, (lu32*)l, 16, 0, 0);
}

#define MFMA_BF16 __builtin_amdgcn_mfma_f32_16x16x32_bf16

// ============================================================================
// GEMMs are STAGING-BANDWIDTH-BOUND (~8 TB/s aggregate memory-system rate;
// model validated on rounds 0-4 within 5%). Optimize staged bytes per output
// under the VGPR (acc) budget and perfect grid balance (blocks % 256 == 0).
// ============================================================================

// ---------------- core A: 256x192 tile (QKV) ----------------
// 512 threads, 8 waves as 2M x 4N, wave 128x48 (acc[8][3]).
// Staged/K-tile: A 32 KB + B 24 KB = 56 KB per 49152 outputs (1.14 B/out).
// LDS 2 x 56 KiB double buffer. 3 phases/K-tile; counted vmcnt(3) at phase 0.
#define LB192   28672     // elements/buffer: Ah 8192 | Al 8192 | Bh 6144 | Bl 6144
#define A192_AL 8192
#define A192_BH 16384
#define A192_BL 22528

__device__ __forceinline__ void mfma3_core192(const bf16* __restrict__ Ah,
                                              const bf16* __restrict__ Al,
                                              const bf16* __restrict__ Bh,
                                              const bf16* __restrict__ Bl,
                                              int bm, int bn,
                                              f32x4 acc[8][3]) {
  __shared__ __align__(16) bf16 smem[2 * LB192];
  const int tid = threadIdx.x;
  const int wave = tid >> 6, lane = tid & 63;
  const int lr4 = lane >> 2;
  // staging source-chunk swizzle (measured 0 bank conflicts)
  const int cgs = (lane & 3) ^ ((lane >> 3) & 3);
  const size_t stageoff = (size_t)lr4 * CDIM + cgs * 8;

  // 56 staging wave-calls of 1 KiB per K-tile, 7 per wave.
  const bf16* gp[7];
  int loff[7];
#pragma unroll
  for (int u = 0; u < 7; ++u) {
    int c = wave * 7 + u;
    const bf16* base;
    int lb;
    if (c < 16)      { base = Ah + (size_t)(bm + c * 16) * CDIM;        lb = c * 512; }
    else if (c < 32) { base = Al + (size_t)(bm + (c - 16) * 16) * CDIM; lb = A192_AL + (c - 16) * 512; }
    else if (c < 44) { base = Bh + (size_t)(bn + (c - 32) * 16) * CDIM; lb = A192_BH + (c - 32) * 512; }
    else             { base = Bl + (size_t)(bn + (c - 44) * 16) * CDIM; lb = A192_BL + (c - 44) * 512; }
    gp[u] = base + stageoff;
    loff[u] = lb;
  }

  const int wr = wave >> 2, wc = wave & 3;          // 2M x 4N wave grid
  const int fr = lane & 15, lg = lane >> 4;
  const int chunk = (lg ^ ((fr >> 1) & 3)) << 3;
  const int arow = wr * 128 + fr;
  const int brow = wc * 48 + fr;

  // prologue: stage K-tile 0 into buffer 0
#pragma unroll
  for (int u = 0; u < 7; ++u) gload_lds16(gp[u], &smem[loff[u]]);

  for (int t = 0; t < 64; ++t) {
    const bf16* cb = &smem[(t & 1) * LB192];
    bf16* nb = &smem[((t + 1) & 1) * LB192];
    const int kk = (t + 1) * 32;
    const bool nlast = (t < 63);

    // ---- phase 0: stage u0..u2 -> counted wait -> barrier -> all A + B0 -> 24 MFMA
    if (nlast) {
      gload_lds16(gp[0] + kk, nb + loff[0]);
      gload_lds16(gp[1] + kk, nb + loff[1]);
      gload_lds16(gp[2] + kk, nb + loff[2]);
      asm volatile("s_waitcnt vmcnt(3)" ::: "memory");
    } else {
      asm volatile("s_waitcnt vmcnt(0)" ::: "memory");
    }
    __builtin_amdgcn_s_barrier();
    asm volatile("" ::: "memory");

    bf16x8 fah[8], fal[8];
#pragma unroll
    for (int i = 0; i < 8; ++i) {
      fah[i] = *(const bf16x8*)&cb[(arow + i * 16) * 32 + chunk];
      fal[i] = *(const bf16x8*)&cb[A192_AL + (arow + i * 16) * 32 + chunk];
    }
    {
      bf16x8 fbh = *(const bf16x8*)&cb[A192_BH + brow * 32 + chunk];
      bf16x8 fbl = *(const bf16x8*)&cb[A192_BL + brow * 32 + chunk];
      __builtin_amdgcn_s_setprio(1);
#pragma unroll
      for (int i = 0; i < 8; ++i) {
        acc[i][0] = MFMA_BF16(fah[i], fbh, acc[i][0], 0, 0, 0);
        acc[i][0] = MFMA_BF16(fah[i], fbl, acc[i][0], 0, 0, 0);
        acc[i][0] = MFMA_BF16(fal[i], fbh, acc[i][0], 0, 0, 0);
      }
      __builtin_amdgcn_s_setprio(0);
    }
    asm volatile("" ::: "memory");
    __builtin_amdgcn_s_barrier();
    asm volatile("" ::: "memory");

    // ---- phases 1..2: stage 2 loads, read B[j], barrier, 24 MFMA ----
#pragma unroll
    for (int j = 1; j < 3; ++j) {
      if (nlast) {
        gload_lds16(gp[2 * j + 1] + kk, nb + loff[2 * j + 1]);
        gload_lds16(gp[2 * j + 2] + kk, nb + loff[2 * j + 2]);
      }
      bf16x8 fbh = *(const bf16x8*)&cb[A192_BH + (brow + j * 16) * 32 + chunk];
      bf16x8 fbl = *(const bf16x8*)&cb[A192_BL + (brow + j * 16) * 32 + chunk];
      asm volatile("" ::: "memory");
      __builtin_amdgcn_s_barrier();
      __builtin_amdgcn_s_setprio(1);
#pragma unroll
      for (int i = 0; i < 8; ++i) {
        acc[i][j] = MFMA_BF16(fah[i], fbh, acc[i][j], 0, 0, 0);
        acc[i][j] = MFMA_BF16(fah[i], fbl, acc[i][j], 0, 0, 0);
        acc[i][j] = MFMA_BF16(fal[i], fbh, acc[i][j], 0, 0, 0);
      }
      __builtin_amdgcn_s_setprio(0);
      asm volatile("" ::: "memory");
      __builtin_amdgcn_s_barrier();
      asm volatile("" ::: "memory");
    }
  }
}

// ---------------- core B: 256x256 tile (wo; r4-proven) ----------------
#define LDS_BUF 32768     // elements/buffer: Ah 8192 | Al 8192 | Bh 8192 | Bl 8192
#define OFF_AL  8192
#define OFF_BH  16384
#define OFF_BL  24576

__device__ __forceinline__ void mfma3_core256(const bf16* __restrict__ Ah,
                                              const bf16* __restrict__ Al,
                                              const bf16* __restrict__ Bh,
                                              const bf16* __restrict__ Bl,
                                              int bm, int bn,
                                              f32x4 acc[8][4]) {
  __shared__ __align__(16) bf16 smem[2 * LDS_BUF];
  const int tid = threadIdx.x;
  const int wave = tid >> 6, lane = tid & 63;
  const int lr4 = lane >> 2;
  const int cgs = (lane & 3) ^ ((lane >> 3) & 3);
  const size_t stageoff = (size_t)lr4 * CDIM + cgs * 8;

  const bf16* gp[8];
  int loff[8];
#pragma unroll
  for (int u = 0; u < 8; ++u) {
    int c = wave * 8 + u;
    const bf16* base;
    int lb;
    if (c < 16)      { base = Ah + (size_t)(bm + c * 16) * CDIM;        lb = c * 512; }
    else if (c < 32) { base = Al + (size_t)(bm + (c - 16) * 16) * CDIM; lb = OFF_AL + (c - 16) * 512; }
    else if (c < 48) { base = Bh + (size_t)(bn + (c - 32) * 16) * CDIM; lb = OFF_BH + (c - 32) * 512; }
    else             { base = Bl + (size_t)(bn + (c - 48) * 16) * CDIM; lb = OFF_BL + (c - 48) * 512; }
    gp[u] = base + stageoff;
    loff[u] = lb;
  }

  const int wr = wave >> 2, wc = wave & 3;
  const int fr = lane & 15, lg = lane >> 4;
  const int chunk = (lg ^ ((fr >> 1) & 3)) << 3;
  const int arow = wr * 128 + fr;
  const int brow = wc * 64 + fr;

#pragma unroll
  for (int u = 0; u < 8; ++u) gload_lds16(gp[u], &smem[loff[u]]);

  for (int t = 0; t < 64; ++t) {
    const bf16* cb = &smem[(t & 1) * LDS_BUF];
    bf16* nb = &smem[((t + 1) & 1) * LDS_BUF];
    const int kk = (t + 1) * 32;
    const bool nlast = (t < 63);

    if (nlast) {
      gload_lds16(gp[0] + kk, nb + loff[0]);
      gload_lds16(gp[1] + kk, nb + loff[1]);
      asm volatile("s_waitcnt vmcnt(2)" ::: "memory");
    } else {
      asm volatile("s_waitcnt vmcnt(0)" ::: "memory");
    }
    __builtin_amdgcn_s_barrier();
    asm volatile("" ::: "memory");

    bf16x8 fah[8], fal[8];
#pragma unroll
    for (int i = 0; i < 8; ++i) {
      fah[i] = *(const bf16x8*)&cb[(arow + i * 16) * 32 + chunk];
      fal[i] = *(const bf16x8*)&cb[OFF_AL + (arow + i * 16) * 32 + chunk];
    }
    {
      bf16x8 fbh = *(const bf16x8*)&cb[OFF_BH + brow * 32 + chunk];
      bf16x8 fbl = *(const bf16x8*)&cb[OFF_BL + brow * 32 + chunk];
      __builtin_amdgcn_s_setprio(1);
#pragma unroll
      for (int i = 0; i < 8; ++i) {
        acc[i][0] = MFMA_BF16(fah[i], fbh, acc[i][0], 0, 0, 0);
        acc[i][0] = MFMA_BF16(fah[i], fbl, acc[i][0], 0, 0, 0);
        acc[i][0] = MFMA_BF16(fal[i], fbh, acc[i][0], 0, 0, 0);
      }
      __builtin_amdgcn_s_setprio(0);
    }
    asm volatile("" ::: "memory");
    __builtin_amdgcn_s_barrier();
    asm volatile("" ::: "memory");

#pragma unroll
    for (int j = 1; j < 4; ++j) {
      if (nlast) {
        gload_lds16(gp[2 * j] + kk, nb + loff[2 * j]);
        gload_lds16(gp[2 * j + 1] + kk, nb + loff[2 * j + 1]);
      }
      bf16x8 fbh = *(const bf16x8*)&cb[OFF_BH + (brow + j * 16) * 32 + chunk];
      bf16x8 fbl = *(const bf16x8*)&cb[OFF_BL + (brow + j * 16) * 32 + chunk];
      asm volatile("" ::: "memory");
      __builtin_amdgcn_s_barrier();
      __builtin_amdgcn_s_setprio(1);
#pragma unroll
      for (int i = 0; i < 8; ++i) {
        acc[i][j] = MFMA_BF16(fah[i], fbh, acc[i][j], 0, 0, 0);
        acc[i][j] = MFMA_BF16(fah[i], fbl, acc[i][j], 0, 0, 0);
        acc[i][j] = MFMA_BF16(fal[i], fbh, acc[i][j], 0, 0, 0);
      }
      __builtin_amdgcn_s_setprio(0);
      asm volatile("" ::: "memory");
      __builtin_amdgcn_s_barrier();
      asm volatile("" ::: "memory");
    }
  }
}

// XCD-aware bijective swizzle (T1)
__device__ __forceinline__ void xcd_swizzle(int& by, int& bx) {
  const int nwgx = gridDim.x;
  const int nwg = nwgx * gridDim.y;           // divisible by 8 for our grids
  const int cpx = nwg >> 3;
  const int bid = blockIdx.y * nwgx + blockIdx.x;
  const int l = (bid & 7) * cpx + (bid >> 3);
  by = l / nwgx;
  bx = l - by * nwgx;
}

// QKV: 256x192 tiles, grid 16x32 = 512 blocks (2 balanced rounds/CU).
__global__ __launch_bounds__(512, 1) void csa_gemm_qkv(const bf16* __restrict__ xh,
                                                       const bf16* __restrict__ xl,
                                                       const bf16* __restrict__ wth,
                                                       const bf16* __restrict__ wtl,
                                                       float* __restrict__ qb,
                                                       float* __restrict__ kb,
                                                       float* __restrict__ vb) {
  f32x4 acc[8][3] = {};
  int by, bx;
  xcd_swizzle(by, bx);
  const int bm = by << 8, bn = bx * 192;
  mfma3_core192(xh, xl, wth, wtl, bm, bn, acc);
  const int wave = threadIdx.x >> 6, lane = threadIdx.x & 63;
  const int wr = wave >> 2, wc = wave & 3;
  const int fr = lane & 15, lg = lane >> 4;
#pragma unroll
  for (int j = 0; j < 3; ++j) {
    // 16-col group; q|k|v boundaries (2048, 2560) are 16-aligned
    int cg = bn + wc * 48 + j * 16;
    float* dst; int ncols, c0;
    if (cg < CDIM)            { dst = qb; ncols = CDIM; c0 = cg; }
    else if (cg < CDIM + 512) { dst = kb; ncols = 512;  c0 = cg - CDIM; }
    else                      { dst = vb; ncols = 512;  c0 = cg - CDIM - 512; }
    int col = c0 + fr;
#pragma unroll
    for (int i = 0; i < 8; ++i) {
      int row0 = bm + wr * 128 + i * 16 + (lg << 2);
#pragma unroll
      for (int r = 0; r < 4; ++r)
        dst[(size_t)(row0 + r) * ncols + col] = acc[i][j][r];
    }
  }
}

// wo: 256x256 tiles, grid 8x32 = 256 blocks (1/CU, balanced).
__global__ __launch_bounds__(512, 1) void csa_gemm_wo(const bf16* __restrict__ ah,
                                                      const bf16* __restrict__ al,
                                                      const bf16* __restrict__ wth,
                                                      const bf16* __restrict__ wtl,
                                                      float* __restrict__ C) {
  f32x4 acc[8][4] = {};
  int by, bx;
  xcd_swizzle(by, bx);
  const int bm = by << 8, bn = bx << 8;
  mfma3_core256(ah, al, wth, wtl, bm, bn, acc);
  const int wave = threadIdx.x >> 6, lane = threadIdx.x & 63;
  const int wr = wave >> 2, wc = wave & 3;
  const int fr = lane & 15, lg = lane >> 4;
#pragma unroll
  for (int i = 0; i < 8; ++i)
#pragma unroll
    for (int j = 0; j < 4; ++j) {
      int row0 = bm + wr * 128 + i * 16 + (lg << 2);
      int col = bn + wc * 64 + j * 16 + fr;
#pragma unroll
      for (int r = 0; r < 4; ++r)
        C[(size_t)(row0 + r) * CDIM + col] = acc[i][j][r];
    }
}

// ---------------- x -> hi/lo bf16 ----------------
__global__ void csa_xconv(const float4* __restrict__ x, bf16x4* __restrict__ xh,
                          bf16x4* __restrict__ xl) {
  int i = blockIdx.x * 256 + threadIdx.x;
  float4 v = x[i];
  bf16x4 h, l;
  h[0] = (bf16)v.x; l[0] = (bf16)(v.x - (float)h[0]);
  h[1] = (bf16)v.y; l[1] = (bf16)(v.y - (float)h[1]);
  h[2] = (bf16)v.z; l[2] = (bf16)(v.z - (float)h[2]);
  h[3] = (bf16)v.w; l[3] = (bf16)(v.w - (float)h[3]);
  xh[i] = h;
  xl[i] = l;
}

// ---------------- W (KxN) -> W^T (NxK) hi/lo bf16 ----------------
__global__ __launch_bounds__(256) void csa_wconv(const float* __restrict__ W, int N,
                                                 bf16* __restrict__ wth,
                                                 bf16* __restrict__ wtl, int rowofs) {
  __shared__ float tile[32][33];
  int k0 = blockIdx.y * 32, n0 = blockIdx.x * 32;
  int tx = threadIdx.x & 31, ty = threadIdx.x >> 5;
#pragma unroll
  for (int r = 0; r < 32; r += 8)
    tile[ty + r][tx] = W[(size_t)(k0 + ty + r) * N + n0 + tx];
  __syncthreads();
#pragma unroll
  for (int r = 0; r < 32; r += 8) {
    int n = ty + r;
    float x = tile[tx][n];
    bf16 h = (bf16)x;
    bf16 l = (bf16)(x - (float)h);
    size_t o = (size_t)(rowofs + n0 + n) * CDIM + k0 + tx;
    wth[o] = h;
    wtl[o] = l;
  }
}

// ---------------- RoPE table ----------------
__global__ void csa_rope_table(float* __restrict__ cost, float* __restrict__ sint) {
  int idx = blockIdx.x * blockDim.x + threadIdx.x;
  if (idx >= TT * HALF) return;
  int t = idx / HALF, i = idx % HALF;
  double freq = pow(10000.0, -(double)i / (double)HALF);
  double ang = (double)t * freq;
  cost[idx] = (float)cos(ang);
  sint[idx] = (float)sin(ang);
}

__global__ void csa_rope_apply(float* __restrict__ buf, const float* __restrict__ cost,
                               const float* __restrict__ sint, int nheads, int total) {
  int idx = blockIdx.x * blockDim.x + threadIdx.x;
  if (idx >= total) return;
  int i = idx % HALF;
  int h = (idx / HALF) % nheads;
  int t = (idx / (HALF * nheads)) % TT;
  int b = idx / (HALF * nheads * TT);
  float c = cost[t * HALF + i], s = sint[t * HALF + i];
  float* p = buf + ((((size_t)b * TT + t) * nheads + h) * HD) + 2 * i;
  float a = p[0], q = p[1];
  p[0] = a * c - q * s;
  p[1] = a * s + q * c;
}

// ---------------- selection path ----------------
__global__ void csa_xpart(const float* __restrict__ x, float* __restrict__ xpart) {
  int d = blockIdx.x * 256 + threadIdx.x;
  int ts = blockIdx.y;
  int b = blockIdx.z;
  float s = 0.f;
  int t0 = ts * (TT / 16);
  for (int t = t0; t < t0 + TT / 16; ++t) s += x[((size_t)b * TT + t) * CDIM + d];
  xpart[((size_t)b * 16 + ts) * CDIM + d] = s;
}

__global__ void csa_kimean(const float* __restrict__ xpart, const float* __restrict__ wik,
                           float* __restrict__ ki) {
  int b = blockIdx.x >> 7;
  int j = blockIdx.x & 127;
  int tid = threadIdx.x;
  float s = 0.f;
  for (int d = tid; d < CDIM; d += 256) {
    float xm = 0.f;
#pragma unroll
    for (int ts = 0; ts < 16; ++ts) xm += xpart[((size_t)b * 16 + ts) * CDIM + d];
    s += xm * wik[(size_t)d * HD + j];
  }
  __shared__ float red[256];
  red[tid] = s;
  __syncthreads();
  for (int off = 128; off > 0; off >>= 1) {
    if (tid < off) red[tid] += red[tid + off];
    __syncthreads();
  }
  if (tid == 0) ki[b * HD + j] = red[0] * (1.f / (float)TT);
}

__global__ void csa_u(const float* __restrict__ wiq, const float* __restrict__ ki,
                      float* __restrict__ u) {
  int idx = blockIdx.x * 256 + threadIdx.x;
  int b = idx / CDIM, d = idx % CDIM;
  float s = 0.f;
#pragma unroll 8
  for (int j = 0; j < HD; ++j) s += wiq[(size_t)d * HD + j] * ki[b * HD + j];
  u[idx] = s;
}

__global__ void csa_scores(const float* __restrict__ x, const float* __restrict__ u,
                           float* __restrict__ sc) {
  int b = blockIdx.x >> 8;
  int t = blockIdx.x & 255;
  int tid = threadIdx.x;
  float s = 0.f;
  for (int d = tid; d < CDIM; d += 256)
    s += x[((size_t)b * TT + t) * CDIM + d] * u[b * CDIM + d];
  __shared__ float red[256];
  red[tid] = s;
  __syncthreads();
  for (int off = 128; off > 0; off >>= 1) {
    if (tid < off) red[tid] += red[tid + off];
    __syncthreads();
  }
  if (tid == 0) sc[blockIdx.x] = red[0];
}

__global__ void csa_topk(const float* __restrict__ sc, int* __restrict__ topk) {
  __shared__ float val[NB];
  __shared__ float rv[256];
  __shared__ int ri[256];
  int b = blockIdx.x, tid = threadIdx.x;
  val[tid] = sc[b * NB + tid];
  __syncthreads();
  for (int it = 0; it < TOPK; ++it) {
    rv[tid] = val[tid];
    ri[tid] = tid;
    __syncthreads();
    for (int off = 128; off > 0; off >>= 1) {
      if (tid < off) {
        if (rv[tid + off] > rv[tid] ||
            (rv[tid + off] == rv[tid] && ri[tid + off] < ri[tid])) {
          rv[tid] = rv[tid + off];
          ri[tid] = ri[tid + off];
        }
      }
      __syncthreads();
    }
    if (tid == 0) {
      topk[b * TOPK + it] = ri[0];
      val[ri[0]] = -INFINITY;
    }
    __syncthreads();
  }
}

// ---------------- compress selected blocks -> split-bf16 MFMA layouts ----------------
__global__ __launch_bounds__(64) void csa_compress(const float* __restrict__ kbuf,
                                                   const float* __restrict__ vbuf,
                                                   const int* __restrict__ topk,
                                                   const float* __restrict__ cwa,
                                                   const float* __restrict__ cwb,
                                                   bf16* __restrict__ ckh,
                                                   bf16* __restrict__ ckl,
                                                   bf16* __restrict__ cvth,
                                                   bf16* __restrict__ cvtl) {
  int blk = blockIdx.x;
  int b = blk / (NKV * TOPK);
  int h = (blk / TOPK) % NKV;
  int j = blk % TOPK;
  int n = topk[b * TOPK + j];
  int l = threadIdx.x;
  float ca0 = cwa[l], ca1 = cwa[l + 64];
  float cb0 = cwb[l], cb1 = cwb[l + 64];
  float kk[RBLK][2], vv[RBLK][2], ar[RBLK], br[RBLK];
#pragma unroll
  for (int r = 0; r < RBLK; ++r) {
    int t = n * RBLK + r;
    size_t base = (((size_t)b * TT + t) * NKV + h) * HD;
    kk[r][0] = kbuf[base + l];
    kk[r][1] = kbuf[base + l + 64];
    vv[r][0] = vbuf[base + l];
    vv[r][1] = vbuf[base + l + 64];
    float pa = kk[r][0] * ca0 + kk[r][1] * ca1;
    float pb = kk[r][0] * cb0 + kk[r][1] * cb1;
    for (int off = 32; off > 0; off >>= 1) {
      pa += __shfl_xor(pa, off);
      pb += __shfl_xor(pb, off);
    }
    ar[r] = pa;
    br[r] = pb;
  }
  float ma = -INFINITY, mb = -INFINITY;
#pragma unroll
  for (int r = 0; r < RBLK; ++r) { ma = fmaxf(ma, ar[r]); mb = fmaxf(mb, br[r]); }
  float ea[RBLK], eb[RBLK], sa = 0.f, sb = 0.f;
#pragma unroll
  for (int r = 0; r < RBLK; ++r) {
    ea[r] = expf(ar[r] - ma); sa += ea[r];
    eb[r] = expf(br[r] - mb); sb += eb[r];
  }
  float isa = 1.f / sa, isb = 1.f / sb;
  float o0 = 0.f, o1 = 0.f, p0 = 0.f, p1 = 0.f;
#pragma unroll
  for (int r = 0; r < RBLK; ++r) {
    float w = 0.5f * (ea[r] * isa + eb[r] * isb);
    o0 += w * kk[r][0]; o1 += w * kk[r][1];
    p0 += w * vv[r][0]; p1 += w * vv[r][1];
  }
  size_t ckbase = ((size_t)(b * NKV + h) * 64 + j) * 128;
  bf16 h0 = (bf16)o0; ckh[ckbase + l] = h0;      ckl[ckbase + l] = (bf16)(o0 - (float)h0);
  bf16 h1 = (bf16)o1; ckh[ckbase + l + 64] = h1; ckl[ckbase + l + 64] = (bf16)(o1 - (float)h1);
  size_t vtbase = (size_t)(b * NKV + h) * (128 * 64);
  bf16 g0 = (bf16)p0; cvth[vtbase + (size_t)l * 64 + j] = g0;
  cvtl[vtbase + (size_t)l * 64 + j] = (bf16)(p0 - (float)g0);
  bf16 g1 = (bf16)p1; cvth[vtbase + (size_t)(l + 64) * 64 + j] = g1;
  cvtl[vtbase + (size_t)(l + 64) * 64 + j] = (bf16)(p1 - (float)g1);
}

// ---------------- MFMA attention: fused q-RoPE, QK^T, softmax, PV ----------------
__global__ __launch_bounds__(256) void csa_attn_mfma(const float* __restrict__ qb,
                                                     const float* __restrict__ cost,
                                                     const float* __restrict__ sint,
                                                     const bf16* __restrict__ ckh_g,
                                                     const bf16* __restrict__ ckl_g,
                                                     const bf16* __restrict__ cvth_g,
                                                     const bf16* __restrict__ cvtl_g,
                                                     bf16* __restrict__ oh_g,
                                                     bf16* __restrict__ ol_g) {
  __shared__ __align__(16) bf16 sck[2][64 * 128];
  __shared__ __align__(16) bf16 sV[2][64 * 64];
  const int tid = threadIdx.x;
  const int wave = tid >> 6, lane = tid & 63;
  const int b = blockIdx.y >> 2, kvh = blockIdx.y & 3;
  const int row0 = blockIdx.x << 7;
  const int wrow = wave << 5;
  const int lr = lane & 15, lg = lane >> 4;
  const float scale = 0.08838834764831845f;  // 1/sqrt(128)

  const bf16* gkh = ckh_g + (size_t)(b * NKV + kvh) * (64 * 128);
  const bf16* gkl = ckl_g + (size_t)(b * NKV + kvh) * (64 * 128);
  const bf16* gvh = cvth_g + (size_t)(b * NKV + kvh) * (128 * 64);
  const bf16* gvl = cvtl_g + (size_t)(b * NKV + kvh) * (128 * 64);

  for (int idx = tid; idx < 1024; idx += 256) {
    int j = idx >> 4, c = idx & 15;
    int dst = (j * 16 + (c ^ (j & 15))) * 8;
    *(uint4*)&sck[0][dst] = *(const uint4*)(gkh + j * 128 + c * 8);
    *(uint4*)&sck[1][dst] = *(const uint4*)(gkl + j * 128 + c * 8);
  }
  for (int idx = tid; idx < 512; idx += 256) {
    int d = idx >> 3, c = idx & 7;
    int dst = (d * 8 + (c ^ (d & 7))) * 8;
    *(uint4*)&sV[0][dst] = *(const uint4*)(gvh + d * 64 + c * 8);
    *(uint4*)&sV[1][dst] = *(const uint4*)(gvl + d * 64 + c * 8);
  }

  bf16x8 qfh[2][4], qfl[2][4];
#pragma unroll
  for (int it = 0; it < 2; ++it)
#pragma unroll
    for (int ks = 0; ks < 4; ++ks) {
      int row = wrow + it * 16 + lr;
      int g = row0 + row;
      int t = g >> 2;
      int hh = kvh * NREP + (g & 3);
      int d0 = ks * 32 + (lg << 3);
      const float* qp = qb + (((size_t)b * TT + t) * NHQ + hh) * HD + d0;
      float4 a = *(const float4*)qp;
      float4 b4 = *(const float4*)(qp + 4);
      float4 cs = *(const float4*)&cost[t * HALF + (d0 >> 1)];
      float4 sn = *(const float4*)&sint[t * HALF + (d0 >> 1)];
      float f[8];
      f[0] = a.x * cs.x - a.y * sn.x;  f[1] = a.x * sn.x + a.y * cs.x;
      f[2] = a.z * cs.y - a.w * sn.y;  f[3] = a.z * sn.y + a.w * cs.y;
      f[4] = b4.x * cs.z - b4.y * sn.z; f[5] = b4.x * sn.z + b4.y * cs.z;
      f[6] = b4.z * cs.w - b4.w * sn.w; f[7] = b4.z * sn.w + b4.w * cs.w;
      bf16x8 h8, l8;
#pragma unroll
      for (int u = 0; u < 8; ++u) {
        h8[u] = (bf16)f[u];
        l8[u] = (bf16)(f[u] - (float)h8[u]);
      }
      qfh[it][ks] = h8;
      qfl[it][ks] = l8;
    }
  __syncthreads();

  f32x4 accS[2][4] = {};
#pragma unroll
  for (int ks = 0; ks < 4; ++ks) {
    bf16x8 kh[4], kl[4];
#pragma unroll
    for (int jt = 0; jt < 4; ++jt) {
      int row = jt * 16 + lr;
      int c = ks * 4 + lg;
      int off = (row * 16 + (c ^ (row & 15))) * 8;
      kh[jt] = *(const bf16x8*)&sck[0][off];
      kl[jt] = *(const bf16x8*)&sck[1][off];
    }
#pragma unroll
    for (int it = 0; it < 2; ++it)
#pragma unroll
      for (int jt = 0; jt < 4; ++jt) {
        accS[it][jt] = MFMA_BF16(qfh[it][ks], kh[jt], accS[it][jt], 0, 0, 0);
        accS[it][jt] = MFMA_BF16(qfh[it][ks], kl[jt], accS[it][jt], 0, 0, 0);
        accS[it][jt] = MFMA_BF16(qfl[it][ks], kh[jt], accS[it][jt], 0, 0, 0);
      }
  }

#pragma unroll
  for (int it = 0; it < 2; ++it)
#pragma unroll
    for (int r = 0; r < 4; ++r) {
      float v0 = accS[it][0][r] * scale, v1 = accS[it][1][r] * scale;
      float v2 = accS[it][2][r] * scale, v3 = accS[it][3][r] * scale;
      float m = fmaxf(fmaxf(v0, v1), fmaxf(v2, v3));
      for (int off = 8; off > 0; off >>= 1) m = fmaxf(m, __shfl_xor(m, off));
      float e0 = expf(v0 - m), e1 = expf(v1 - m), e2 = expf(v2 - m), e3 = expf(v3 - m);
      float s = e0 + e1 + e2 + e3;
      for (int off = 8; off > 0; off >>= 1) s += __shfl_xor(s, off);
      float inv = 1.f / s;
      accS[it][0][r] = e0 * inv; accS[it][1][r] = e1 * inv;
      accS[it][2][r] = e2 * inv; accS[it][3][r] = e3 * inv;
    }

  __syncthreads();

#pragma unroll
  for (int it = 0; it < 2; ++it)
#pragma unroll
    for (int jt = 0; jt < 4; ++jt)
#pragma unroll
      for (int r = 0; r < 4; ++r) {
        int row = wrow + it * 16 + (lg << 2) + r;
        int k = jt * 16 + lr;
        float p = accS[it][jt][r];
        bf16 ph = (bf16)p;
        int c = k >> 3;
        int off = (row * 8 + (c ^ (row & 7))) * 8 + (k & 7);
        sck[0][off] = ph;
        sck[1][off] = (bf16)(p - (float)ph);
      }
  __syncthreads();

  for (int half = 0; half < 2; ++half) {
    if (half) {
      __syncthreads();
      for (int idx = tid; idx < 512; idx += 256) {
        int d = idx >> 3, c = idx & 7;
        int dst = (d * 8 + (c ^ (d & 7))) * 8;
        *(uint4*)&sV[0][dst] = *(const uint4*)(gvh + (64 + d) * 64 + c * 8);
        *(uint4*)&sV[1][dst] = *(const uint4*)(gvl + (64 + d) * 64 + c * 8);
      }
      __syncthreads();
    }
    f32x4 accO[2][4] = {};
#pragma unroll
    for (int ks = 0; ks < 2; ++ks) {
      bf16x8 pah[2], pal[2], vh[4], vl[4];
#pragma unroll
      for (int it = 0; it < 2; ++it) {
        int row = wrow + it * 16 + lr;
        int c = ks * 4 + lg;
        int off = (row * 8 + (c ^ (row & 7))) * 8;
        pah[it] = *(const bf16x8*)&sck[0][off];
        pal[it] = *(const bf16x8*)&sck[1][off];
      }
#pragma unroll
      for (int jt = 0; jt < 4; ++jt) {
        int d = jt * 16 + lr;
        int c = ks * 4 + lg;
        int off = (d * 8 + (c ^ (d & 7))) * 8;
        vh[jt] = *(const bf16x8*)&sV[0][off];
        vl[jt] = *(const bf16x8*)&sV[1][off];
      }
#pragma unroll
      for (int it = 0; it < 2; ++it)
#pragma unroll
        for (int jt = 0; jt < 4; ++jt) {
          accO[it][jt] = MFMA_BF16(pah[it], vh[jt], accO[it][jt], 0, 0, 0);
          accO[it][jt] = MFMA_BF16(pah[it], vl[jt], accO[it][jt], 0, 0, 0);
          accO[it][jt] = MFMA_BF16(pal[it], vh[jt], accO[it][jt], 0, 0, 0);
        }
    }
#pragma unroll
    for (int it = 0; it < 2; ++it)
#pragma unroll
      for (int jt = 0; jt < 4; ++jt)
#pragma unroll
        for (int r = 0; r < 4; ++r) {
          int row = wrow + it * 16 + (lg << 2) + r;
          int g = row0 + row;
          int t = g >> 2;
          int hh = kvh * NREP + (g & 3);
          size_t ob = (((size_t)b * TT + t) * NHQ + hh) * HD + half * 64 + jt * 16 + lr;
          float o = accO[it][jt][r];
          bf16 oh = (bf16)o;
          oh_g[ob] = oh;
          ol_g[ob] = (bf16)(o - (float)oh);
        }
  }
}

// ---------------- launch ----------------
extern "C" void kernel_launch(void* const* d_in, const int* in_sizes, int n_in,
                              void* d_out, int out_size, void* d_ws, size_t ws_size,
                              hipStream_t stream) {
  const float* x   = (const float*)d_in[0];
  const float* wq  = (const float*)d_in[1];
  const float* wk  = (const float*)d_in[2];
  const float* wv  = (const float*)d_in[3];
  const float* wo  = (const float*)d_in[4];
  const float* wiq = (const float*)d_in[5];
  const float* wik = (const float*)d_in[6];
  const float* cwa = (const float*)d_in[7];
  const float* cwb = (const float*)d_in[8];
  float* out = (float*)d_out;

  float* qb = out;  // q fp32 lives in d_out until the final GEMM overwrites it

  float* ws = (float*)d_ws;
  float* kb   = ws;
  float* vb   = kb + (size_t)MROWS * 512;
  bf16*  xh   = (bf16*)(vb + (size_t)MROWS * 512);
  bf16*  xl   = xh + XELE;
  bf16*  wqh  = xl + XELE;
  bf16*  wql  = wqh + (size_t)NQKV * CDIM;
  float* cost = (float*)(wql + (size_t)NQKV * CDIM);
  float* sint = cost + (size_t)TT * HALF;
  float* xpart = sint + (size_t)TT * HALF;
  float* ki   = xpart + (size_t)BB * 16 * CDIM;
  float* u    = ki + BB * HD;
  float* sc   = u + BB * CDIM;
  bf16*  ckh  = (bf16*)(sc + BB * NB);
  bf16*  ckl  = ckh + (size_t)BB * NKV * 64 * 128;
  bf16*  cvth = ckl + (size_t)BB * NKV * 64 * 128;
  bf16*  cvtl = cvth + (size_t)BB * NKV * 128 * 64;
  int* topk   = (int*)(cvtl + (size_t)BB * NKV * 128 * 64);
  bf16* oh  = xh;   // attention output hi/lo reuses xh/xl
  bf16* ol_ = xl;
  bf16* woh = wqh;  // wo^T hi/lo reuses wq^T region (converted after QKV GEMM)
  bf16* wol = wql;

  // 1. input conversions
  csa_xconv<<<(XELE / 4) / 256, 256, 0, stream>>>((const float4*)x, (bf16x4*)xh, (bf16x4*)xl);
  csa_wconv<<<dim3(CDIM / 32, CDIM / 32), 256, 0, stream>>>(wq, CDIM, wqh, wql, 0);
  csa_wconv<<<dim3(512 / 32, CDIM / 32), 256, 0, stream>>>(wk, 512, wqh, wql, CDIM);
  csa_wconv<<<dim3(512 / 32, CDIM / 32), 256, 0, stream>>>(wv, 512, wqh, wql, CDIM + 512);

  // 2. fused QKV projection (256x192 tiles, 512 blocks = 2 balanced rounds/CU)
  csa_gemm_qkv<<<dim3(NQKV / 192, MROWS / 256), 512, 0, stream>>>(xh, xl, wqh, wql, qb, kb, vb);

  // 3. wo transpose+split (reuses wq^T region)
  csa_wconv<<<dim3(CDIM / 32, CDIM / 32), 256, 0, stream>>>(wo, CDIM, woh, wol, 0);

  // 4. RoPE table + apply to k only (q RoPE fused into attention)
  csa_rope_table<<<(TT * HALF + 255) / 256, 256, 0, stream>>>(cost, sint);
  csa_rope_apply<<<(BB * TT * NKV * HALF + 255) / 256, 256, 0, stream>>>(kb, cost, sint, NKV, BB * TT * NKV * HALF);

  // 5. selection
  csa_xpart<<<dim3(CDIM / 256, 16, BB), 256, 0, stream>>>(x, xpart);
  csa_kimean<<<BB * HD, 256, 0, stream>>>(xpart, wik, ki);
  csa_u<<<(BB * CDIM) / 256, 256, 0, stream>>>(wiq, ki, u);
  csa_scores<<<BB * NB, 256, 0, stream>>>(x, u, sc);
  csa_topk<<<BB, 256, 0, stream>>>(sc, topk);

  // 6. compress selected blocks -> split-bf16 MFMA layouts
  csa_compress<<<BB * NKV * TOPK, 64, 0, stream>>>(kb, vb, topk, cwa, cwb, ckh, ckl, cvth, cvtl);

  // 7. MFMA attention (fused q-RoPE) -> split-bf16 output
  csa_attn_mfma<<<dim3((TT * NREP) / 128, BB * NKV), 256, 0, stream>>>(qb, cost, sint, ckh, ckl, cvth, cvtl, oh, ol_);

  // 8. output projection (256x256 tiles, 256 blocks = 1/CU) -> d_out
  csa_gemm_wo<<<dim3(CDIM / 256, MROWS / 256), 512, 0, stream>>>(oh, ol_, woh, wol, out);
}

// Round 6
// 655.037 us; speedup vs baseline: 1.1977x; 1.1226x over previous
//
#include <hip/hip_runtime.h>
#include <math.h>
#include <stdint.h>

// ---------------- problem constants ----------------
#define BB    2
#define TT    4096
#define CDIM  2048
#define NHQ   16
#define NKV   4
#define HD    128
#define HALF  64
#define NREP  4
#define RBLK  16
#define NB    256
#define TOPK  64

#define MROWS (BB * TT)                    // 8192
#define NQKV  (CDIM + 2 * NKV * HD)        // 3072
#define XELE  ((size_t)MROWS * CDIM)       // 16,777,216

typedef __bf16 bf16;
typedef __bf16 bf16x4 __attribute__((ext_vector_type(4)));
typedef __bf16 bf16x8 __attribute__((ext_vector_type(8)));
typedef float f32x4 __attribute__((ext_vector_type(4)));

typedef __attribute__((address_space(1))) unsigned int gu32;
typedef __attribute__((address_space(3))) unsigned int lu32;

__device__ __forceinline__ void gload_lds16(const void* g, void* l) {
  void* gv = const_cast<void*>(g);
  __builtin_amdgcn_global_load_lds((gu32*)gv, (lu32*)l, 16, 0, 0);
}

#define MFMA_BF16 __builtin_amdgcn_mfma_f32_16x16x32_bf16

// ============================================================================
// GEMMs are STAGING-BANDWIDTH-BOUND at ~28-30 GB/s per CU (validated r0-r5;
// time = staged_bytes_per_CU / rate). Register file caps per-wave acc+state at
// 256 (2 waves/SIMD), which pins QKV at 256x192/2-round (1.14 B/out) and wo at
// 256x256/1-round (1.0 B/out) -- both kernels are at their structural floor.
// DO NOT change their geometry without re-deriving the acc/VGPR budget.
// ============================================================================

// ---------------- core A: 256x192 tile (QKV) ----------------
#define LB192   28672     // elements/buffer: Ah 8192 | Al 8192 | Bh 6144 | Bl 6144
#define A192_AL 8192
#define A192_BH 16384
#define A192_BL 22528

__device__ __forceinline__ void mfma3_core192(const bf16* __restrict__ Ah,
                                              const bf16* __restrict__ Al,
                                              const bf16* __restrict__ Bh,
                                              const bf16* __restrict__ Bl,
                                              int bm, int bn,
                                              f32x4 acc[8][3]) {
  __shared__ __align__(16) bf16 smem[2 * LB192];
  const int tid = threadIdx.x;
  const int wave = tid >> 6, lane = tid & 63;
  const int lr4 = lane >> 2;
  // staging source-chunk swizzle (measured 0 bank conflicts)
  const int cgs = (lane & 3) ^ ((lane >> 3) & 3);
  const size_t stageoff = (size_t)lr4 * CDIM + cgs * 8;

  // 56 staging wave-calls of 1 KiB per K-tile, 7 per wave.
  const bf16* gp[7];
  int loff[7];
#pragma unroll
  for (int u = 0; u < 7; ++u) {
    int c = wave * 7 + u;
    const bf16* base;
    int lb;
    if (c < 16)      { base = Ah + (size_t)(bm + c * 16) * CDIM;        lb = c * 512; }
    else if (c < 32) { base = Al + (size_t)(bm + (c - 16) * 16) * CDIM; lb = A192_AL + (c - 16) * 512; }
    else if (c < 44) { base = Bh + (size_t)(bn + (c - 32) * 16) * CDIM; lb = A192_BH + (c - 32) * 512; }
    else             { base = Bl + (size_t)(bn + (c - 44) * 16) * CDIM; lb = A192_BL + (c - 44) * 512; }
    gp[u] = base + stageoff;
    loff[u] = lb;
  }

  const int wr = wave >> 2, wc = wave & 3;          // 2M x 4N wave grid
  const int fr = lane & 15, lg = lane >> 4;
  const int chunk = (lg ^ ((fr >> 1) & 3)) << 3;
  const int arow = wr * 128 + fr;
  const int brow = wc * 48 + fr;

  // prologue: stage K-tile 0 into buffer 0
#pragma unroll
  for (int u = 0; u < 7; ++u) gload_lds16(gp[u], &smem[loff[u]]);

  for (int t = 0; t < 64; ++t) {
    const bf16* cb = &smem[(t & 1) * LB192];
    bf16* nb = &smem[((t + 1) & 1) * LB192];
    const int kk = (t + 1) * 32;
    const bool nlast = (t < 63);

    // ---- phase 0: stage u0..u2 -> counted wait -> barrier -> all A + B0 -> 24 MFMA
    if (nlast) {
      gload_lds16(gp[0] + kk, nb + loff[0]);
      gload_lds16(gp[1] + kk, nb + loff[1]);
      gload_lds16(gp[2] + kk, nb + loff[2]);
      asm volatile("s_waitcnt vmcnt(3)" ::: "memory");
    } else {
      asm volatile("s_waitcnt vmcnt(0)" ::: "memory");
    }
    __builtin_amdgcn_s_barrier();
    asm volatile("" ::: "memory");

    bf16x8 fah[8], fal[8];
#pragma unroll
    for (int i = 0; i < 8; ++i) {
      fah[i] = *(const bf16x8*)&cb[(arow + i * 16) * 32 + chunk];
      fal[i] = *(const bf16x8*)&cb[A192_AL + (arow + i * 16) * 32 + chunk];
    }
    {
      bf16x8 fbh = *(const bf16x8*)&cb[A192_BH + brow * 32 + chunk];
      bf16x8 fbl = *(const bf16x8*)&cb[A192_BL + brow * 32 + chunk];
      __builtin_amdgcn_s_setprio(1);
#pragma unroll
      for (int i = 0; i < 8; ++i) {
        acc[i][0] = MFMA_BF16(fah[i], fbh, acc[i][0], 0, 0, 0);
        acc[i][0] = MFMA_BF16(fah[i], fbl, acc[i][0], 0, 0, 0);
        acc[i][0] = MFMA_BF16(fal[i], fbh, acc[i][0], 0, 0, 0);
      }
      __builtin_amdgcn_s_setprio(0);
    }
    asm volatile("" ::: "memory");
    __builtin_amdgcn_s_barrier();
    asm volatile("" ::: "memory");

    // ---- phases 1..2: stage 2 loads, read B[j], barrier, 24 MFMA ----
#pragma unroll
    for (int j = 1; j < 3; ++j) {
      if (nlast) {
        gload_lds16(gp[2 * j + 1] + kk, nb + loff[2 * j + 1]);
        gload_lds16(gp[2 * j + 2] + kk, nb + loff[2 * j + 2]);
      }
      bf16x8 fbh = *(const bf16x8*)&cb[A192_BH + (brow + j * 16) * 32 + chunk];
      bf16x8 fbl = *(const bf16x8*)&cb[A192_BL + (brow + j * 16) * 32 + chunk];
      asm volatile("" ::: "memory");
      __builtin_amdgcn_s_barrier();
      __builtin_amdgcn_s_setprio(1);
#pragma unroll
      for (int i = 0; i < 8; ++i) {
        acc[i][j] = MFMA_BF16(fah[i], fbh, acc[i][j], 0, 0, 0);
        acc[i][j] = MFMA_BF16(fah[i], fbl, acc[i][j], 0, 0, 0);
        acc[i][j] = MFMA_BF16(fal[i], fbh, acc[i][j], 0, 0, 0);
      }
      __builtin_amdgcn_s_setprio(0);
      asm volatile("" ::: "memory");
      __builtin_amdgcn_s_barrier();
      asm volatile("" ::: "memory");
    }
  }
}

// ---------------- core B: 256x256 tile (wo) ----------------
#define LDS_BUF 32768     // elements/buffer: Ah 8192 | Al 8192 | Bh 8192 | Bl 8192
#define OFF_AL  8192
#define OFF_BH  16384
#define OFF_BL  24576

__device__ __forceinline__ void mfma3_core256(const bf16* __restrict__ Ah,
                                              const bf16* __restrict__ Al,
                                              const bf16* __restrict__ Bh,
                                              const bf16* __restrict__ Bl,
                                              int bm, int bn,
                                              f32x4 acc[8][4]) {
  __shared__ __align__(16) bf16 smem[2 * LDS_BUF];
  const int tid = threadIdx.x;
  const int wave = tid >> 6, lane = tid & 63;
  const int lr4 = lane >> 2;
  const int cgs = (lane & 3) ^ ((lane >> 3) & 3);
  const size_t stageoff = (size_t)lr4 * CDIM + cgs * 8;

  const bf16* gp[8];
  int loff[8];
#pragma unroll
  for (int u = 0; u < 8; ++u) {
    int c = wave * 8 + u;
    const bf16* base;
    int lb;
    if (c < 16)      { base = Ah + (size_t)(bm + c * 16) * CDIM;        lb = c * 512; }
    else if (c < 32) { base = Al + (size_t)(bm + (c - 16) * 16) * CDIM; lb = OFF_AL + (c - 16) * 512; }
    else if (c < 48) { base = Bh + (size_t)(bn + (c - 32) * 16) * CDIM; lb = OFF_BH + (c - 32) * 512; }
    else             { base = Bl + (size_t)(bn + (c - 48) * 16) * CDIM; lb = OFF_BL + (c - 48) * 512; }
    gp[u] = base + stageoff;
    loff[u] = lb;
  }

  const int wr = wave >> 2, wc = wave & 3;
  const int fr = lane & 15, lg = lane >> 4;
  const int chunk = (lg ^ ((fr >> 1) & 3)) << 3;
  const int arow = wr * 128 + fr;
  const int brow = wc * 64 + fr;

#pragma unroll
  for (int u = 0; u < 8; ++u) gload_lds16(gp[u], &smem[loff[u]]);

  for (int t = 0; t < 64; ++t) {
    const bf16* cb = &smem[(t & 1) * LDS_BUF];
    bf16* nb = &smem[((t + 1) & 1) * LDS_BUF];
    const int kk = (t + 1) * 32;
    const bool nlast = (t < 63);

    if (nlast) {
      gload_lds16(gp[0] + kk, nb + loff[0]);
      gload_lds16(gp[1] + kk, nb + loff[1]);
      asm volatile("s_waitcnt vmcnt(2)" ::: "memory");
    } else {
      asm volatile("s_waitcnt vmcnt(0)" ::: "memory");
    }
    __builtin_amdgcn_s_barrier();
    asm volatile("" ::: "memory");

    bf16x8 fah[8], fal[8];
#pragma unroll
    for (int i = 0; i < 8; ++i) {
      fah[i] = *(const bf16x8*)&cb[(arow + i * 16) * 32 + chunk];
      fal[i] = *(const bf16x8*)&cb[OFF_AL + (arow + i * 16) * 32 + chunk];
    }
    {
      bf16x8 fbh = *(const bf16x8*)&cb[OFF_BH + brow * 32 + chunk];
      bf16x8 fbl = *(const bf16x8*)&cb[OFF_BL + brow * 32 + chunk];
      __builtin_amdgcn_s_setprio(1);
#pragma unroll
      for (int i = 0; i < 8; ++i) {
        acc[i][0] = MFMA_BF16(fah[i], fbh, acc[i][0], 0, 0, 0);
        acc[i][0] = MFMA_BF16(fah[i], fbl, acc[i][0], 0, 0, 0);
        acc[i][0] = MFMA_BF16(fal[i], fbh, acc[i][0], 0, 0, 0);
      }
      __builtin_amdgcn_s_setprio(0);
    }
    asm volatile("" ::: "memory");
    __builtin_amdgcn_s_barrier();
    asm volatile("" ::: "memory");

#pragma unroll
    for (int j = 1; j < 4; ++j) {
      if (nlast) {
        gload_lds16(gp[2 * j] + kk, nb + loff[2 * j]);
        gload_lds16(gp[2 * j + 1] + kk, nb + loff[2 * j + 1]);
      }
      bf16x8 fbh = *(const bf16x8*)&cb[OFF_BH + (brow + j * 16) * 32 + chunk];
      bf16x8 fbl = *(const bf16x8*)&cb[OFF_BL + (brow + j * 16) * 32 + chunk];
      asm volatile("" ::: "memory");
      __builtin_amdgcn_s_barrier();
      __builtin_amdgcn_s_setprio(1);
#pragma unroll
      for (int i = 0; i < 8; ++i) {
        acc[i][j] = MFMA_BF16(fah[i], fbh, acc[i][j], 0, 0, 0);
        acc[i][j] = MFMA_BF16(fah[i], fbl, acc[i][j], 0, 0, 0);
        acc[i][j] = MFMA_BF16(fal[i], fbh, acc[i][j], 0, 0, 0);
      }
      __builtin_amdgcn_s_setprio(0);
      asm volatile("" ::: "memory");
      __builtin_amdgcn_s_barrier();
      asm volatile("" ::: "memory");
    }
  }
}

// XCD-aware bijective swizzle (T1)
__device__ __forceinline__ void xcd_swizzle(int& by, int& bx) {
  const int nwgx = gridDim.x;
  const int nwg = nwgx * gridDim.y;           // divisible by 8 for our grids
  const int cpx = nwg >> 3;
  const int bid = blockIdx.y * nwgx + blockIdx.x;
  const int l = (bid & 7) * cpx + (bid >> 3);
  by = l / nwgx;
  bx = l - by * nwgx;
}

// QKV: 256x192 tiles, grid 16x32 = 512 blocks (2 balanced rounds/CU).
__global__ __launch_bounds__(512, 1) void csa_gemm_qkv(const bf16* __restrict__ xh,
                                                       const bf16* __restrict__ xl,
                                                       const bf16* __restrict__ wth,
                                                       const bf16* __restrict__ wtl,
                                                       float* __restrict__ qb,
                                                       float* __restrict__ kb,
                                                       float* __restrict__ vb) {
  f32x4 acc[8][3] = {};
  int by, bx;
  xcd_swizzle(by, bx);
  const int bm = by << 8, bn = bx * 192;
  mfma3_core192(xh, xl, wth, wtl, bm, bn, acc);
  const int wave = threadIdx.x >> 6, lane = threadIdx.x & 63;
  const int wr = wave >> 2, wc = wave & 3;
  const int fr = lane & 15, lg = lane >> 4;
#pragma unroll
  for (int j = 0; j < 3; ++j) {
    // 16-col group; q|k|v boundaries (2048, 2560) are 16-aligned
    int cg = bn + wc * 48 + j * 16;
    float* dst; int ncols, c0;
    if (cg < CDIM)            { dst = qb; ncols = CDIM; c0 = cg; }
    else if (cg < CDIM + 512) { dst = kb; ncols = 512;  c0 = cg - CDIM; }
    else                      { dst = vb; ncols = 512;  c0 = cg - CDIM - 512; }
    int col = c0 + fr;
#pragma unroll
    for (int i = 0; i < 8; ++i) {
      int row0 = bm + wr * 128 + i * 16 + (lg << 2);
#pragma unroll
      for (int r = 0; r < 4; ++r)
        dst[(size_t)(row0 + r) * ncols + col] = acc[i][j][r];
    }
  }
}

// wo: 256x256 tiles, grid 8x32 = 256 blocks (1/CU, balanced).
__global__ __launch_bounds__(512, 1) void csa_gemm_wo(const bf16* __restrict__ ah,
                                                      const bf16* __restrict__ al,
                                                      const bf16* __restrict__ wth,
                                                      const bf16* __restrict__ wtl,
                                                      float* __restrict__ C) {
  f32x4 acc[8][4] = {};
  int by, bx;
  xcd_swizzle(by, bx);
  const int bm = by << 8, bn = bx << 8;
  mfma3_core256(ah, al, wth, wtl, bm, bn, acc);
  const int wave = threadIdx.x >> 6, lane = threadIdx.x & 63;
  const int wr = wave >> 2, wc = wave & 3;
  const int fr = lane & 15, lg = lane >> 4;
#pragma unroll
  for (int i = 0; i < 8; ++i)
#pragma unroll
    for (int j = 0; j < 4; ++j) {
      int row0 = bm + wr * 128 + i * 16 + (lg << 2);
      int col = bn + wc * 64 + j * 16 + fr;
#pragma unroll
      for (int r = 0; r < 4; ++r)
        C[(size_t)(row0 + r) * CDIM + col] = acc[i][j][r];
    }
}

// ---------------- x -> hi/lo bf16 ----------------
__global__ void csa_xconv(const float4* __restrict__ x, bf16x4* __restrict__ xh,
                          bf16x4* __restrict__ xl) {
  int i = blockIdx.x * 256 + threadIdx.x;
  float4 v = x[i];
  bf16x4 h, l;
  h[0] = (bf16)v.x; l[0] = (bf16)(v.x - (float)h[0]);
  h[1] = (bf16)v.y; l[1] = (bf16)(v.y - (float)h[1]);
  h[2] = (bf16)v.z; l[2] = (bf16)(v.z - (float)h[2]);
  h[3] = (bf16)v.w; l[3] = (bf16)(v.w - (float)h[3]);
  xh[i] = h;
  xl[i] = l;
}

// ---------------- W (KxN) -> W^T (NxK) hi/lo bf16 ----------------
__global__ __launch_bounds__(256) void csa_wconv(const float* __restrict__ W, int N,
                                                 bf16* __restrict__ wth,
                                                 bf16* __restrict__ wtl, int rowofs) {
  __shared__ float tile[32][33];
  int k0 = blockIdx.y * 32, n0 = blockIdx.x * 32;
  int tx = threadIdx.x & 31, ty = threadIdx.x >> 5;
#pragma unroll
  for (int r = 0; r < 32; r += 8)
    tile[ty + r][tx] = W[(size_t)(k0 + ty + r) * N + n0 + tx];
  __syncthreads();
#pragma unroll
  for (int r = 0; r < 32; r += 8) {
    int n = ty + r;
    float x = tile[tx][n];
    bf16 h = (bf16)x;
    bf16 l = (bf16)(x - (float)h);
    size_t o = (size_t)(rowofs + n0 + n) * CDIM + k0 + tx;
    wth[o] = h;
    wtl[o] = l;
  }
}

// merged wq/wk/wv transpose+split: grid (64+16+16, 64); bx selects source
__global__ __launch_bounds__(256) void csa_wconv3(const float* __restrict__ wq,
                                                  const float* __restrict__ wk,
                                                  const float* __restrict__ wv,
                                                  bf16* __restrict__ wth,
                                                  bf16* __restrict__ wtl) {
  __shared__ float tile[32][33];
  int bx = blockIdx.x;
  const float* W; int N, rowofs, n0;
  if (bx < 64)      { W = wq; N = 2048; rowofs = 0;    n0 = bx * 32; }
  else if (bx < 80) { W = wk; N = 512;  rowofs = 2048; n0 = (bx - 64) * 32; }
  else              { W = wv; N = 512;  rowofs = 2560; n0 = (bx - 80) * 32; }
  int k0 = blockIdx.y * 32;
  int tx = threadIdx.x & 31, ty = threadIdx.x >> 5;
#pragma unroll
  for (int r = 0; r < 32; r += 8)
    tile[ty + r][tx] = W[(size_t)(k0 + ty + r) * N + n0 + tx];
  __syncthreads();
#pragma unroll
  for (int r = 0; r < 32; r += 8) {
    int n = ty + r;
    float x = tile[tx][n];
    bf16 h = (bf16)x;
    bf16 l = (bf16)(x - (float)h);
    size_t o = (size_t)(rowofs + n0 + n) * CDIM + k0 + tx;
    wth[o] = h;
    wtl[o] = l;
  }
}

// ---------------- RoPE table ----------------
__global__ void csa_rope_table(float* __restrict__ cost, float* __restrict__ sint) {
  int idx = blockIdx.x * blockDim.x + threadIdx.x;
  if (idx >= TT * HALF) return;
  int t = idx / HALF, i = idx % HALF;
  double freq = pow(10000.0, -(double)i / (double)HALF);
  double ang = (double)t * freq;
  cost[idx] = (float)cos(ang);
  sint[idx] = (float)sin(ang);
}

__global__ void csa_rope_apply(float* __restrict__ buf, const float* __restrict__ cost,
                               const float* __restrict__ sint, int nheads, int total) {
  int idx = blockIdx.x * blockDim.x + threadIdx.x;
  if (idx >= total) return;
  int i = idx % HALF;
  int h = (idx / HALF) % nheads;
  int t = (idx / (HALF * nheads)) % TT;
  int b = idx / (HALF * nheads * TT);
  float c = cost[t * HALF + i], s = sint[t * HALF + i];
  float* p = buf + ((((size_t)b * TT + t) * nheads + h) * HD) + 2 * i;
  float a = p[0], q = p[1];
  p[0] = a * c - q * s;
  p[1] = a * s + q * c;
}

// ---------------- selection path ----------------
__global__ void csa_xpart(const float* __restrict__ x, float* __restrict__ xpart) {
  int d = blockIdx.x * 256 + threadIdx.x;
  int ts = blockIdx.y;
  int b = blockIdx.z;
  float s = 0.f;
  int t0 = ts * (TT / 16);
  for (int t = t0; t < t0 + TT / 16; ++t) s += x[((size_t)b * TT + t) * CDIM + d];
  xpart[((size_t)b * 16 + ts) * CDIM + d] = s;
}

__global__ void csa_kimean(const float* __restrict__ xpart, const float* __restrict__ wik,
                           float* __restrict__ ki) {
  int b = blockIdx.x >> 7;
  int j = blockIdx.x & 127;
  int tid = threadIdx.x;
  float s = 0.f;
  for (int d = tid; d < CDIM; d += 256) {
    float xm = 0.f;
#pragma unroll
    for (int ts = 0; ts < 16; ++ts) xm += xpart[((size_t)b * 16 + ts) * CDIM + d];
    s += xm * wik[(size_t)d * HD + j];
  }
  __shared__ float red[256];
  red[tid] = s;
  __syncthreads();
  for (int off = 128; off > 0; off >>= 1) {
    if (tid < off) red[tid] += red[tid + off];
    __syncthreads();
  }
  if (tid == 0) ki[b * HD + j] = red[0] * (1.f / (float)TT);
}

__global__ void csa_u(const float* __restrict__ wiq, const float* __restrict__ ki,
                      float* __restrict__ u) {
  int idx = blockIdx.x * 256 + threadIdx.x;
  int b = idx / CDIM, d = idx % CDIM;
  float s = 0.f;
#pragma unroll 8
  for (int j = 0; j < HD; ++j) s += wiq[(size_t)d * HD + j] * ki[b * HD + j];
  u[idx] = s;
}

__global__ void csa_scores(const float* __restrict__ x, const float* __restrict__ u,
                           float* __restrict__ sc) {
  int b = blockIdx.x >> 8;
  int t = blockIdx.x & 255;
  int tid = threadIdx.x;
  float s = 0.f;
  for (int d = tid; d < CDIM; d += 256)
    s += x[((size_t)b * TT + t) * CDIM + d] * u[b * CDIM + d];
  __shared__ float red[256];
  red[tid] = s;
  __syncthreads();
  for (int off = 128; off > 0; off >>= 1) {
    if (tid < off) red[tid] += red[tid + off];
    __syncthreads();
  }
  if (tid == 0) sc[blockIdx.x] = red[0];
}

// bitonic full sort of 256 scores by (val desc, idx asc); top-64 = first 64.
// Produces the IDENTICAL topk[] array as the old iterative-max loop.
__global__ __launch_bounds__(256) void csa_topk(const float* __restrict__ sc,
                                                int* __restrict__ topk) {
  __shared__ float v[NB];
  __shared__ int ix[NB];
  int b = blockIdx.x, tid = threadIdx.x;
  v[tid] = sc[b * NB + tid];
  ix[tid] = tid;
  __syncthreads();
  for (int k = 2; k <= NB; k <<= 1) {
    for (int j = k >> 1; j > 0; j >>= 1) {
      int p = tid ^ j;
      if (p > tid) {
        float va = v[tid], vb = v[p];
        int ia = ix[tid], ib = ix[p];
        bool abefore = (va > vb) || (va == vb && ia < ib);
        bool up = ((tid & k) == 0);
        if (up ? !abefore : abefore) {
          v[tid] = vb; ix[tid] = ib;
          v[p] = va;  ix[p] = ia;
        }
      }
      __syncthreads();
    }
  }
  if (tid < TOPK) topk[b * TOPK + tid] = ix[tid];
}

// ---------------- compress selected blocks -> split-bf16 MFMA layouts ----------------
__global__ __launch_bounds__(64) void csa_compress(const float* __restrict__ kbuf,
                                                   const float* __restrict__ vbuf,
                                                   const int* __restrict__ topk,
                                                   const float* __restrict__ cwa,
                                                   const float* __restrict__ cwb,
                                                   bf16* __restrict__ ckh,
                                                   bf16* __restrict__ ckl,
                                                   bf16* __restrict__ cvth,
                                                   bf16* __restrict__ cvtl) {
  int blk = blockIdx.x;
  int b = blk / (NKV * TOPK);
  int h = (blk / TOPK) % NKV;
  int j = blk % TOPK;
  int n = topk[b * TOPK + j];
  int l = threadIdx.x;
  float ca0 = cwa[l], ca1 = cwa[l + 64];
  float cb0 = cwb[l], cb1 = cwb[l + 64];
  float kk[RBLK][2], vv[RBLK][2], ar[RBLK], br[RBLK];
#pragma unroll
  for (int r = 0; r < RBLK; ++r) {
    int t = n * RBLK + r;
    size_t base = (((size_t)b * TT + t) * NKV + h) * HD;
    kk[r][0] = kbuf[base + l];
    kk[r][1] = kbuf[base + l + 64];
    vv[r][0] = vbuf[base + l];
    vv[r][1] = vbuf[base + l + 64];
    float pa = kk[r][0] * ca0 + kk[r][1] * ca1;
    float pb = kk[r][0] * cb0 + kk[r][1] * cb1;
    for (int off = 32; off > 0; off >>= 1) {
      pa += __shfl_xor(pa, off);
      pb += __shfl_xor(pb, off);
    }
    ar[r] = pa;
    br[r] = pb;
  }
  float ma = -INFINITY, mb = -INFINITY;
#pragma unroll
  for (int r = 0; r < RBLK; ++r) { ma = fmaxf(ma, ar[r]); mb = fmaxf(mb, br[r]); }
  float ea[RBLK], eb[RBLK], sa = 0.f, sb = 0.f;
#pragma unroll
  for (int r = 0; r < RBLK; ++r) {
    ea[r] = expf(ar[r] - ma); sa += ea[r];
    eb[r] = expf(br[r] - mb); sb += eb[r];
  }
  float isa = 1.f / sa, isb = 1.f / sb;
  float o0 = 0.f, o1 = 0.f, p0 = 0.f, p1 = 0.f;
#pragma unroll
  for (int r = 0; r < RBLK; ++r) {
    float w = 0.5f * (ea[r] * isa + eb[r] * isb);
    o0 += w * kk[r][0]; o1 += w * kk[r][1];
    p0 += w * vv[r][0]; p1 += w * vv[r][1];
  }
  size_t ckbase = ((size_t)(b * NKV + h) * 64 + j) * 128;
  bf16 h0 = (bf16)o0; ckh[ckbase + l] = h0;      ckl[ckbase + l] = (bf16)(o0 - (float)h0);
  bf16 h1 = (bf16)o1; ckh[ckbase + l + 64] = h1; ckl[ckbase + l + 64] = (bf16)(o1 - (float)h1);
  size_t vtbase = (size_t)(b * NKV + h) * (128 * 64);
  bf16 g0 = (bf16)p0; cvth[vtbase + (size_t)l * 64 + j] = g0;
  cvtl[vtbase + (size_t)l * 64 + j] = (bf16)(p0 - (float)g0);
  bf16 g1 = (bf16)p1; cvth[vtbase + (size_t)(l + 64) * 64 + j] = g1;
  cvtl[vtbase + (size_t)(l + 64) * 64 + j] = (bf16)(p1 - (float)g1);
}

// ---------------- MFMA attention: fused q-RoPE, QK^T, softmax, PV ----------------
__global__ __launch_bounds__(256) void csa_attn_mfma(const float* __restrict__ qb,
                                                     const float* __restrict__ cost,
                                                     const float* __restrict__ sint,
                                                     const bf16* __restrict__ ckh_g,
                                                     const bf16* __restrict__ ckl_g,
                                                     const bf16* __restrict__ cvth_g,
                                                     const bf16* __restrict__ cvtl_g,
                                                     bf16* __restrict__ oh_g,
                                                     bf16* __restrict__ ol_g) {
  __shared__ __align__(16) bf16 sck[2][64 * 128];
  __shared__ __align__(16) bf16 sV[2][64 * 64];
  const int tid = threadIdx.x;
  const int wave = tid >> 6, lane = tid & 63;
  const int b = blockIdx.y >> 2, kvh = blockIdx.y & 3;
  const int row0 = blockIdx.x << 7;
  const int wrow = wave << 5;
  const int lr = lane & 15, lg = lane >> 4;
  const float scale = 0.08838834764831845f;  // 1/sqrt(128)

  const bf16* gkh = ckh_g + (size_t)(b * NKV + kvh) * (64 * 128);
  const bf16* gkl = ckl_g + (size_t)(b * NKV + kvh) * (64 * 128);
  const bf16* gvh = cvth_g + (size_t)(b * NKV + kvh) * (128 * 64);
  const bf16* gvl = cvtl_g + (size_t)(b * NKV + kvh) * (128 * 64);

  for (int idx = tid; idx < 1024; idx += 256) {
    int j = idx >> 4, c = idx & 15;
    int dst = (j * 16 + (c ^ (j & 15))) * 8;
    *(uint4*)&sck[0][dst] = *(const uint4*)(gkh + j * 128 + c * 8);
    *(uint4*)&sck[1][dst] = *(const uint4*)(gkl + j * 128 + c * 8);
  }
  for (int idx = tid; idx < 512; idx += 256) {
    int d = idx >> 3, c = idx & 7;
    int dst = (d * 8 + (c ^ (d & 7))) * 8;
    *(uint4*)&sV[0][dst] = *(const uint4*)(gvh + d * 64 + c * 8);
    *(uint4*)&sV[1][dst] = *(const uint4*)(gvl + d * 64 + c * 8);
  }

  bf16x8 qfh[2][4], qfl[2][4];
#pragma unroll
  for (int it = 0; it < 2; ++it)
#pragma unroll
    for (int ks = 0; ks < 4; ++ks) {
      int row = wrow + it * 16 + lr;
      int g = row0 + row;
      int t = g >> 2;
      int hh = kvh * NREP + (g & 3);
      int d0 = ks * 32 + (lg << 3);
      const float* qp = qb + (((size_t)b * TT + t) * NHQ + hh) * HD + d0;
      float4 a = *(const float4*)qp;
      float4 b4 = *(const float4*)(qp + 4);
      float4 cs = *(const float4*)&cost[t * HALF + (d0 >> 1)];
      float4 sn = *(const float4*)&sint[t * HALF + (d0 >> 1)];
      float f[8];
      f[0] = a.x * cs.x - a.y * sn.x;  f[1] = a.x * sn.x + a.y * cs.x;
      f[2] = a.z * cs.y - a.w * sn.y;  f[3] = a.z * sn.y + a.w * cs.y;
      f[4] = b4.x * cs.z - b4.y * sn.z; f[5] = b4.x * sn.z + b4.y * cs.z;
      f[6] = b4.z * cs.w - b4.w * sn.w; f[7] = b4.z * sn.w + b4.w * cs.w;
      bf16x8 h8, l8;
#pragma unroll
      for (int u = 0; u < 8; ++u) {
        h8[u] = (bf16)f[u];
        l8[u] = (bf16)(f[u] - (float)h8[u]);
      }
      qfh[it][ks] = h8;
      qfl[it][ks] = l8;
    }
  __syncthreads();

  f32x4 accS[2][4] = {};
#pragma unroll
  for (int ks = 0; ks < 4; ++ks) {
    bf16x8 kh[4], kl[4];
#pragma unroll
    for (int jt = 0; jt < 4; ++jt) {
      int row = jt * 16 + lr;
      int c = ks * 4 + lg;
      int off = (row * 16 + (c ^ (row & 15))) * 8;
      kh[jt] = *(const bf16x8*)&sck[0][off];
      kl[jt] = *(const bf16x8*)&sck[1][off];
    }
    __builtin_amdgcn_s_setprio(1);
#pragma unroll
    for (int it = 0; it < 2; ++it)
#pragma unroll
      for (int jt = 0; jt < 4; ++jt) {
        accS[it][jt] = MFMA_BF16(qfh[it][ks], kh[jt], accS[it][jt], 0, 0, 0);
        accS[it][jt] = MFMA_BF16(qfh[it][ks], kl[jt], accS[it][jt], 0, 0, 0);
        accS[it][jt] = MFMA_BF16(qfl[it][ks], kh[jt], accS[it][jt], 0, 0, 0);
      }
    __builtin_amdgcn_s_setprio(0);
  }

#pragma unroll
  for (int it = 0; it < 2; ++it)
#pragma unroll
    for (int r = 0; r < 4; ++r) {
      float v0 = accS[it][0][r] * scale, v1 = accS[it][1][r] * scale;
      float v2 = accS[it][2][r] * scale, v3 = accS[it][3][r] * scale;
      float m = fmaxf(fmaxf(v0, v1), fmaxf(v2, v3));
      for (int off = 8; off > 0; off >>= 1) m = fmaxf(m, __shfl_xor(m, off));
      float e0 = expf(v0 - m), e1 = expf(v1 - m), e2 = expf(v2 - m), e3 = expf(v3 - m);
      float s = e0 + e1 + e2 + e3;
      for (int off = 8; off > 0; off >>= 1) s += __shfl_xor(s, off);
      float inv = 1.f / s;
      accS[it][0][r] = e0 * inv; accS[it][1][r] = e1 * inv;
      accS[it][2][r] = e2 * inv; accS[it][3][r] = e3 * inv;
    }

  __syncthreads();

#pragma unroll
  for (int it = 0; it < 2; ++it)
#pragma unroll
    for (int jt = 0; jt < 4; ++jt)
#pragma unroll
      for (int r = 0; r < 4; ++r) {
        int row = wrow + it * 16 + (lg << 2) + r;
        int k = jt * 16 + lr;
        float p = accS[it][jt][r];
        bf16 ph = (bf16)p;
        int c = k >> 3;
        int off = (row * 8 + (c ^ (row & 7))) * 8 + (k & 7);
        sck[0][off] = ph;
        sck[1][off] = (bf16)(p - (float)ph);
      }
  __syncthreads();

  for (int half = 0; half < 2; ++half) {
    if (half) {
      __syncthreads();
      for (int idx = tid; idx < 512; idx += 256) {
        int d = idx >> 3, c = idx & 7;
        int dst = (d * 8 + (c ^ (d & 7))) * 8;
        *(uint4*)&sV[0][dst] = *(const uint4*)(gvh + (64 + d) * 64 + c * 8);
        *(uint4*)&sV[1][dst] = *(const uint4*)(gvl + (64 + d) * 64 + c * 8);
      }
      __syncthreads();
    }
    f32x4 accO[2][4] = {};
#pragma unroll
    for (int ks = 0; ks < 2; ++ks) {
      bf16x8 pah[2], pal[2], vh[4], vl[4];
#pragma unroll
      for (int it = 0; it < 2; ++it) {
        int row = wrow + it * 16 + lr;
        int c = ks * 4 + lg;
        int off = (row * 8 + (c ^ (row & 7))) * 8;
        pah[it] = *(const bf16x8*)&sck[0][off];
        pal[it] = *(const bf16x8*)&sck[1][off];
      }
#pragma unroll
      for (int jt = 0; jt < 4; ++jt) {
        int d = jt * 16 + lr;
        int c = ks * 4 + lg;
        int off = (d * 8 + (c ^ (d & 7))) * 8;
        vh[jt] = *(const bf16x8*)&sV[0][off];
        vl[jt] = *(const bf16x8*)&sV[1][off];
      }
      __builtin_amdgcn_s_setprio(1);
#pragma unroll
      for (int it = 0; it < 2; ++it)
#pragma unroll
        for (int jt = 0; jt < 4; ++jt) {
          accO[it][jt] = MFMA_BF16(pah[it], vh[jt], accO[it][jt], 0, 0, 0);
          accO[it][jt] = MFMA_BF16(pah[it], vl[jt], accO[it][jt], 0, 0, 0);
          accO[it][jt] = MFMA_BF16(pal[it], vh[jt], accO[it][jt], 0, 0, 0);
        }
      __builtin_amdgcn_s_setprio(0);
    }
#pragma unroll
    for (int it = 0; it < 2; ++it)
#pragma unroll
      for (int jt = 0; jt < 4; ++jt)
#pragma unroll
        for (int r = 0; r < 4; ++r) {
          int row = wrow + it * 16 + (lg << 2) + r;
          int g = row0 + row;
          int t = g >> 2;
          int hh = kvh * NREP + (g & 3);
          size_t ob = (((size_t)b * TT + t) * NHQ + hh) * HD + half * 64 + jt * 16 + lr;
          float o = accO[it][jt][r];
          bf16 oh = (bf16)o;
          oh_g[ob] = oh;
          ol_g[ob] = (bf16)(o - (float)oh);
        }
  }
}

// ---------------- launch ----------------
extern "C" void kernel_launch(void* const* d_in, const int* in_sizes, int n_in,
                              void* d_out, int out_size, void* d_ws, size_t ws_size,
                              hipStream_t stream) {
  const float* x   = (const float*)d_in[0];
  const float* wq  = (const float*)d_in[1];
  const float* wk  = (const float*)d_in[2];
  const float* wv  = (const float*)d_in[3];
  const float* wo  = (const float*)d_in[4];
  const float* wiq = (const float*)d_in[5];
  const float* wik = (const float*)d_in[6];
  const float* cwa = (const float*)d_in[7];
  const float* cwb = (const float*)d_in[8];
  float* out = (float*)d_out;

  float* qb = out;  // q fp32 lives in d_out until the final GEMM overwrites it

  float* ws = (float*)d_ws;
  float* kb   = ws;
  float* vb   = kb + (size_t)MROWS * 512;
  bf16*  xh   = (bf16*)(vb + (size_t)MROWS * 512);
  bf16*  xl   = xh + XELE;
  bf16*  wqh  = xl + XELE;
  bf16*  wql  = wqh + (size_t)NQKV * CDIM;
  float* cost = (float*)(wql + (size_t)NQKV * CDIM);
  float* sint = cost + (size_t)TT * HALF;
  float* xpart = sint + (size_t)TT * HALF;
  float* ki   = xpart + (size_t)BB * 16 * CDIM;
  float* u    = ki + BB * HD;
  float* sc   = u + BB * CDIM;
  bf16*  ckh  = (bf16*)(sc + BB * NB);
  bf16*  ckl  = ckh + (size_t)BB * NKV * 64 * 128;
  bf16*  cvth = ckl + (size_t)BB * NKV * 64 * 128;
  bf16*  cvtl = cvth + (size_t)BB * NKV * 128 * 64;
  int* topk   = (int*)(cvtl + (size_t)BB * NKV * 128 * 64);
  bf16* oh  = xh;   // attention output hi/lo reuses xh/xl
  bf16* ol_ = xl;
  bf16* woh = wqh;  // wo^T hi/lo reuses wq^T region (converted after QKV GEMM)
  bf16* wol = wql;

  // 1. input conversions (wq/wk/wv merged into one launch)
  csa_xconv<<<(XELE / 4) / 256, 256, 0, stream>>>((const float4*)x, (bf16x4*)xh, (bf16x4*)xl);
  csa_wconv3<<<dim3(96, CDIM / 32), 256, 0, stream>>>(wq, wk, wv, wqh, wql);

  // 2. fused QKV projection (256x192 tiles, 512 blocks = 2 balanced rounds/CU)
  csa_gemm_qkv<<<dim3(NQKV / 192, MROWS / 256), 512, 0, stream>>>(xh, xl, wqh, wql, qb, kb, vb);

  // 3. wo transpose+split (reuses wq^T region)
  csa_wconv<<<dim3(CDIM / 32, CDIM / 32), 256, 0, stream>>>(wo, CDIM, woh, wol, 0);

  // 4. RoPE table + apply to k only (q RoPE fused into attention)
  csa_rope_table<<<(TT * HALF + 255) / 256, 256, 0, stream>>>(cost, sint);
  csa_rope_apply<<<(BB * TT * NKV * HALF + 255) / 256, 256, 0, stream>>>(kb, cost, sint, NKV, BB * TT * NKV * HALF);

  // 5. selection
  csa_xpart<<<dim3(CDIM / 256, 16, BB), 256, 0, stream>>>(x, xpart);
  csa_kimean<<<BB * HD, 256, 0, stream>>>(xpart, wik, ki);
  csa_u<<<(BB * CDIM) / 256, 256, 0, stream>>>(wiq, ki, u);
  csa_scores<<<BB * NB, 256, 0, stream>>>(x, u, sc);
  csa_topk<<<BB, 256, 0, stream>>>(sc, topk);

  // 6. compress selected blocks -> split-bf16 MFMA layouts
  csa_compress<<<BB * NKV * TOPK, 64, 0, stream>>>(kb, vb, topk, cwa, cwb, ckh, ckl, cvth, cvtl);

  // 7. MFMA attention (fused q-RoPE) -> split-bf16 output
  csa_attn_mfma<<<dim3((TT * NREP) / 128, BB * NKV), 256, 0, stream>>>(qb, cost, sint, ckh, ckl, cvth, cvtl, oh, ol_);

  // 8. output projection (256x256 tiles, 256 blocks = 1/CU) -> d_out
  csa_gemm_wo<<<dim3(CDIM / 256, MROWS / 256), 512, 0, stream>>>(oh, ol_, woh, wol, out);
}